// Round 1
// baseline (729.922 us; speedup 1.0000x reference)
//
#include <hip/hip_runtime.h>
#include <math.h>

#define NB 8
#define NCLS 8
#define NGU 6
#define NBI 14
#define HF 512
#define WF 512
#define HH 256
#define WH 256

// mean-field tile params
#define TSX 32
#define TSY 16
#define TPX 34
#define TPY 18

static __device__ __forceinline__ void ac_prep(int o, float scale, int insz,
                                               int& i0, int& i1, float& f) {
    float s = (float)o * scale;
    int ii = (int)floorf(s);
    if (ii > insz - 1) ii = insz - 1;
    if (ii < 0) ii = 0;
    i0 = ii;
    i1 = (ii + 1 < insz) ? (ii + 1) : (insz - 1);
    f = s - (float)ii;
}

// ---------------- K0: fill p buffers with bias ----------------
__global__ void k_fill_bias(float* __restrict__ out, const float* __restrict__ b, int HW) {
    int total = NB * 3 * HW;
    int idx = blockIdx.x * blockDim.x + threadIdx.x;
    if (idx >= total) return;
    int o = (idx / HW) % 3;
    out[idx] = b[o];
}

// ---------------- K1: skip 1x1 projection (channel-chunked, atomic) ----------------
__global__ void k_skip_proj(const float* __restrict__ feat, const float* __restrict__ w,
                            float* __restrict__ out, int C, int HW, int nch) {
    __shared__ float sw[3 * 512];
    for (int i = threadIdx.x; i < 3 * C; i += blockDim.x) sw[i] = w[i];
    __syncthreads();
    int total = NB * HW * nch;
    for (int idx = blockIdx.x * blockDim.x + threadIdx.x; idx < total;
         idx += gridDim.x * blockDim.x) {
        int hw = idx % HW;
        int t = idx / HW;
        int ch = t % nch;
        int n = t / nch;
        int c0 = ch * 64;
        const float* fp = feat + ((size_t)n * C + c0) * HW + hw;
        float a0 = 0.f, a1 = 0.f, a2 = 0.f;
        #pragma unroll 8
        for (int c = 0; c < 64; ++c) {
            float v = fp[(size_t)c * HW];
            a0 = fmaf(sw[c0 + c], v, a0);
            a1 = fmaf(sw[C + c0 + c], v, a1);
            a2 = fmaf(sw[2 * C + c0 + c], v, a2);
        }
        float* op = out + (size_t)n * 3 * HW + hw;
        atomicAdd(&op[0], a0);
        atomicAdd(&op[HW], a1);
        atomicAdd(&op[2 * HW], a2);
    }
}

// ---------------- K2: fused (sum of 4 upsampled levels / 4) + guidance concat ----------------
__global__ void k_fused_guid(const float* __restrict__ image,
                             const float* __restrict__ p0, const float* __restrict__ p1,
                             const float* __restrict__ p2, const float* __restrict__ p3,
                             float* __restrict__ guid) {
    const int HW = HF * WF;
    int total = NB * HW;
    int idx = blockIdx.x * blockDim.x + threadIdx.x;
    if (idx >= total) return;
    int n = idx / HW, r = idx - n * HW;
    int y = r / WF, x = r - y * WF;

    const float* ps[4] = {p0, p1, p2, p3};
    const int ss[4] = {256, 128, 64, 32};
    float f[3] = {0.f, 0.f, 0.f};
    #pragma unroll
    for (int l = 0; l < 4; ++l) {
        int s = ss[l];
        float scale = (float)(s - 1) / 511.0f;
        int y0, y1, x0, x1;
        float fy, fx;
        ac_prep(y, scale, s, y0, y1, fy);
        ac_prep(x, scale, s, x0, x1, fx);
        const float* pb = ps[l] + (size_t)n * 3 * s * s;
        #pragma unroll
        for (int o = 0; o < 3; ++o) {
            const float* pp = pb + (size_t)o * s * s;
            float v00 = pp[y0 * s + x0], v01 = pp[y0 * s + x1];
            float v10 = pp[y1 * s + x0], v11 = pp[y1 * s + x1];
            float r0 = v00 * (1.f - fy) + v10 * fy;
            float r1 = v01 * (1.f - fy) + v11 * fy;
            f[o] += r0 * (1.f - fx) + r1 * fx;
        }
    }
    float* gp = guid + (size_t)n * NGU * HW + y * WF + x;
    const float* ip = image + (size_t)n * 3 * HW + y * WF + x;
    #pragma unroll
    for (int o = 0; o < 3; ++o) gp[(size_t)o * HW] = ip[(size_t)o * HW];
    #pragma unroll
    for (int o = 0; o < 3; ++o) gp[(size_t)(3 + o) * HW] = f[o] * 0.25f;
}

// ---------------- K3: generic align-corners bilinear resize ----------------
__global__ void k_resize(const float* __restrict__ in, float* __restrict__ out,
                         int NCtot, int Hi, int Wi, int Ho, int Wo) {
    int total = NCtot * Ho * Wo;
    int idx = blockIdx.x * blockDim.x + threadIdx.x;
    if (idx >= total) return;
    float sy = (float)(Hi - 1) / (float)(Ho - 1);
    float sx = (float)(Wi - 1) / (float)(Wo - 1);
    int nc = idx / (Ho * Wo), r = idx - nc * (Ho * Wo);
    int yo = r / Wo, xo = r - yo * Wo;
    int y0, y1, x0, x1;
    float fy, fx;
    ac_prep(yo, sy, Hi, y0, y1, fy);
    ac_prep(xo, sx, Wi, x0, x1, fx);
    const float* ip = in + (size_t)nc * Hi * Wi;
    float v00 = ip[y0 * Wi + x0], v01 = ip[y0 * Wi + x1];
    float v10 = ip[y1 * Wi + x0], v11 = ip[y1 * Wi + x1];
    float r0 = v00 * (1.f - fy) + v10 * fy;
    float r1 = v01 * (1.f - fy) + v11 * fy;
    out[idx] = r0 * (1.f - fx) + r1 * fx;
}

// ---------------- K4: channel softmax (8 classes) ----------------
__global__ void k_softmax8(const float* __restrict__ in, float* __restrict__ out, int HW) {
    int total = NB * HW;
    int idx = blockIdx.x * blockDim.x + threadIdx.x;
    if (idx >= total) return;
    int n = idx / HW, hw = idx - n * HW;
    const float* ip = in + (size_t)n * NCLS * HW + hw;
    float u[8];
    #pragma unroll
    for (int o = 0; o < 8; ++o) u[o] = ip[(size_t)o * HW];
    float mx = u[0];
    #pragma unroll
    for (int o = 1; o < 8; ++o) mx = fmaxf(mx, u[o]);
    float s = 0.f;
    #pragma unroll
    for (int o = 0; o < 8; ++o) { u[o] = __expf(u[o] - mx); s += u[o]; }
    float inv = 1.f / s;
    float* op = out + (size_t)n * NCLS * HW + hw;
    #pragma unroll
    for (int o = 0; o < 8; ++o) op[(size_t)o * HW] = u[o] * inv;
}

// ---------------- K5: one mean-field iteration (fused convs + compat + softmax) ----------------
__global__ __launch_bounds__(128) void k_mf_iter(
    const float* __restrict__ unary, const float* __restrict__ guid,
    const float* __restrict__ Qin, float* __restrict__ Qout,
    const float* __restrict__ wsp, const float* __restrict__ wbil,
    const float* __restrict__ cw, int H, int W) {
    __shared__ float s_tile[NBI * TPY * TPX];  // 8568 floats
    __shared__ float s_wbT[NBI * 9 * 8];       // transposed: [ci*9+tap][o]
    __shared__ float s_wsp[NCLS * 9];
    __shared__ float s_cw[64];

    const int tid = threadIdx.x;
    const int n = blockIdx.z;
    const int bx = blockIdx.x * TSX;
    const int by = blockIdx.y * TSY;
    const int HW = H * W;

    for (int i = tid; i < NCLS * NBI * 9; i += 128) {
        int o = i / (NBI * 9);
        int r = i - o * (NBI * 9);
        s_wbT[r * 8 + o] = wbil[i];
    }
    for (int i = tid; i < NCLS * 9; i += 128) s_wsp[i] = wsp[i];
    if (tid < 64) s_cw[tid] = cw[tid];

    const int y0 = by - 1, x0 = bx - 1;
    for (int i = tid; i < NBI * TPY * TPX; i += 128) {
        int ch = i / (TPY * TPX);
        int r = i - ch * (TPY * TPX);
        int yy = r / TPX;
        int xx = r - yy * TPX;
        int gy = y0 + yy, gx = x0 + xx;
        float v = 0.f;
        if ((unsigned)gy < (unsigned)H && (unsigned)gx < (unsigned)W) {
            v = (ch < NCLS) ? Qin[((size_t)n * NCLS + ch) * HW + gy * W + gx]
                            : guid[((size_t)n * NGU + (ch - NCLS)) * HW + gy * W + gx];
        }
        s_tile[i] = v;
    }
    __syncthreads();

    const int tx = tid & 15;
    const int ty = tid >> 4;

    float acc[2][2][8];
    #pragma unroll
    for (int a = 0; a < 2; ++a)
        #pragma unroll
        for (int b = 0; b < 2; ++b)
            #pragma unroll
            for (int o = 0; o < 8; ++o) acc[a][b][o] = 0.f;

    for (int ci = 0; ci < NBI; ++ci) {
        float v[4][4];
        const float* tp = &s_tile[ci * (TPY * TPX) + (2 * ty) * TPX + 2 * tx];
        #pragma unroll
        for (int rr = 0; rr < 4; ++rr)
            #pragma unroll
            for (int cc = 0; cc < 4; ++cc) v[rr][cc] = tp[rr * TPX + cc];

        #pragma unroll
        for (int ky = 0; ky < 3; ++ky) {
            #pragma unroll
            for (int kx = 0; kx < 3; ++kx) {
                const int tap = ky * 3 + kx;
                const float4 w0 = *reinterpret_cast<const float4*>(&s_wbT[(ci * 9 + tap) * 8]);
                const float4 w1 = *reinterpret_cast<const float4*>(&s_wbT[(ci * 9 + tap) * 8 + 4]);
                #pragma unroll
                for (int a = 0; a < 2; ++a) {
                    #pragma unroll
                    for (int b = 0; b < 2; ++b) {
                        const float vv = v[a + ky][b + kx];
                        acc[a][b][0] = fmaf(w0.x, vv, acc[a][b][0]);
                        acc[a][b][1] = fmaf(w0.y, vv, acc[a][b][1]);
                        acc[a][b][2] = fmaf(w0.z, vv, acc[a][b][2]);
                        acc[a][b][3] = fmaf(w0.w, vv, acc[a][b][3]);
                        acc[a][b][4] = fmaf(w1.x, vv, acc[a][b][4]);
                        acc[a][b][5] = fmaf(w1.y, vv, acc[a][b][5]);
                        acc[a][b][6] = fmaf(w1.z, vv, acc[a][b][6]);
                        acc[a][b][7] = fmaf(w1.w, vv, acc[a][b][7]);
                    }
                }
            }
        }
        if (ci < NCLS) {
            #pragma unroll
            for (int ky = 0; ky < 3; ++ky) {
                #pragma unroll
                for (int kx = 0; kx < 3; ++kx) {
                    const float wv = s_wsp[ci * 9 + ky * 3 + kx];
                    #pragma unroll
                    for (int a = 0; a < 2; ++a)
                        #pragma unroll
                        for (int b = 0; b < 2; ++b)
                            acc[a][b][ci] = fmaf(wv, v[a + ky][b + kx], acc[a][b][ci]);
                }
            }
        }
    }

    #pragma unroll
    for (int a = 0; a < 2; ++a) {
        #pragma unroll
        for (int b = 0; b < 2; ++b) {
            const int y = by + 2 * ty + a;
            const int x = bx + 2 * tx + b;
            const float* up = unary + (size_t)n * NCLS * HW + y * W + x;
            float u[8];
            #pragma unroll
            for (int o = 0; o < 8; ++o) {
                const float4 c0 = *reinterpret_cast<const float4*>(&s_cw[o * 8]);
                const float4 c1 = *reinterpret_cast<const float4*>(&s_cw[o * 8 + 4]);
                float m = c0.x * acc[a][b][0] + c0.y * acc[a][b][1] +
                          c0.z * acc[a][b][2] + c0.w * acc[a][b][3] +
                          c1.x * acc[a][b][4] + c1.y * acc[a][b][5] +
                          c1.z * acc[a][b][6] + c1.w * acc[a][b][7];
                u[o] = up[(size_t)o * HW] - m;
            }
            float mx = u[0];
            #pragma unroll
            for (int o = 1; o < 8; ++o) mx = fmaxf(mx, u[o]);
            float s = 0.f;
            #pragma unroll
            for (int o = 0; o < 8; ++o) { u[o] = __expf(u[o] - mx); s += u[o]; }
            const float inv = 1.f / s;
            float* qp = Qout + (size_t)n * NCLS * HW + y * W + x;
            #pragma unroll
            for (int o = 0; o < 8; ++o) qp[(size_t)o * HW] = u[o] * inv;
        }
    }
}

// ---------------- K6: out = 0.5 * upsample(Q_down) ----------------
__global__ void k_upcombine(const float* __restrict__ Qd, float* __restrict__ out) {
    const int HW = HF * WF;
    int total = NB * NCLS * HW;
    int idx = blockIdx.x * blockDim.x + threadIdx.x;
    if (idx >= total) return;
    int nc = idx / HW, r = idx - nc * HW;
    int y = r / WF, x = r - y * WF;
    const float sc = 255.f / 511.f;
    int y0, y1, x0, x1;
    float fy, fx;
    ac_prep(y, sc, HH, y0, y1, fy);
    ac_prep(x, sc, WH, x0, x1, fx);
    const float* qp = Qd + (size_t)nc * (HH * WH);
    float v00 = qp[y0 * WH + x0], v01 = qp[y0 * WH + x1];
    float v10 = qp[y1 * WH + x0], v11 = qp[y1 * WH + x1];
    float r0 = v00 * (1.f - fy) + v10 * fy;
    float r1 = v01 * (1.f - fy) + v11 * fy;
    out[idx] = 0.5f * (r0 * (1.f - fx) + r1 * fx);
}

// ---------------- K7: out += 0.5 * Q_full ----------------
__global__ void k_addhalf(const float4* __restrict__ Qf, float4* __restrict__ out, int total4) {
    int idx = blockIdx.x * blockDim.x + threadIdx.x;
    if (idx >= total4) return;
    float4 a = out[idx];
    float4 q = Qf[idx];
    a.x = fmaf(0.5f, q.x, a.x);
    a.y = fmaf(0.5f, q.y, a.y);
    a.z = fmaf(0.5f, q.z, a.z);
    a.w = fmaf(0.5f, q.w, a.w);
    out[idx] = a;
}

static inline int cdiv(int a, int b) { return (a + b - 1) / b; }

extern "C" void kernel_launch(void* const* d_in, const int* in_sizes, int n_in,
                              void* d_out, int out_size, void* d_ws, size_t ws_size,
                              hipStream_t stream) {
    const float* logits = (const float*)d_in[0];
    const float* image = (const float*)d_in[1];
    const float* skip0 = (const float*)d_in[2];
    const float* skip1 = (const float*)d_in[3];
    const float* skip2 = (const float*)d_in[4];
    const float* skip3 = (const float*)d_in[5];
    const float* spatial_w = (const float*)d_in[6];
    const float* bilateral_w = (const float*)d_in[7];
    const float* compat_w = (const float*)d_in[8];
    const float* skip_w0 = (const float*)d_in[9];
    const float* skip_b0 = (const float*)d_in[10];
    const float* skip_w1 = (const float*)d_in[11];
    const float* skip_b1 = (const float*)d_in[12];
    const float* skip_w2 = (const float*)d_in[13];
    const float* skip_b2 = (const float*)d_in[14];
    const float* skip_w3 = (const float*)d_in[15];
    const float* skip_b3 = (const float*)d_in[16];
    float* out = (float*)d_out;
    float* ws = (float*)d_ws;

    // workspace layout (floats). Region A is time-shared:
    //  phase 1: p0..p3 ; phase 2 (after guid built): logits_d/guid_d/Qa_d/Qb_d ;
    //  phase 3 (after down folded into out): Qa_f
    float* p0 = ws + 0;
    float* p1 = p0 + (size_t)NB * 3 * 256 * 256;
    float* p2 = p1 + (size_t)NB * 3 * 128 * 128;
    float* p3 = p2 + (size_t)NB * 3 * 64 * 64;
    float* logits_d = ws + 0;
    float* guid_d = ws + 4194304;
    float* Qa_d = ws + 7340032;
    float* Qb_d = ws + 11534336;
    float* Qa_f = ws + 0;
    float* guid = ws + 16777216;
    float* Qb_f = ws + 29360128;

    const int HWf = HF * WF;   // 262144
    const int HWh = HH * WH;   // 65536

    // --- skip projections ---
    k_fill_bias<<<cdiv(NB * 3 * 65536, 256), 256, 0, stream>>>(p0, skip_b0, 65536);
    k_fill_bias<<<cdiv(NB * 3 * 16384, 256), 256, 0, stream>>>(p1, skip_b1, 16384);
    k_fill_bias<<<cdiv(NB * 3 * 4096, 256), 256, 0, stream>>>(p2, skip_b2, 4096);
    k_fill_bias<<<cdiv(NB * 3 * 1024, 256), 256, 0, stream>>>(p3, skip_b3, 1024);

    k_skip_proj<<<cdiv(NB * 65536 * 1, 256), 256, 0, stream>>>(skip0, skip_w0, p0, 64, 65536, 1);
    k_skip_proj<<<cdiv(NB * 16384 * 2, 256), 256, 0, stream>>>(skip1, skip_w1, p1, 128, 16384, 2);
    k_skip_proj<<<cdiv(NB * 4096 * 4, 256), 256, 0, stream>>>(skip2, skip_w2, p2, 256, 4096, 4);
    k_skip_proj<<<cdiv(NB * 1024 * 8, 256), 256, 0, stream>>>(skip3, skip_w3, p3, 512, 1024, 8);

    // --- fused + guidance ---
    k_fused_guid<<<cdiv(NB * HWf, 256), 256, 0, stream>>>(image, p0, p1, p2, p3, guid);

    // --- downsample logits & guidance ---
    k_resize<<<cdiv(NB * NCLS * HWh, 256), 256, 0, stream>>>(logits, logits_d, NB * NCLS, HF, WF, HH, WH);
    k_resize<<<cdiv(NB * NGU * HWh, 256), 256, 0, stream>>>(guid, guid_d, NB * NGU, HF, WF, HH, WH);

    // --- half-res mean field ---
    k_softmax8<<<cdiv(NB * HWh, 256), 256, 0, stream>>>(logits_d, Qa_d, HWh);
    {
        dim3 grid(WH / TSX, HH / TSY, NB);
        k_mf_iter<<<grid, 128, 0, stream>>>(logits_d, guid_d, Qa_d, Qb_d, spatial_w, bilateral_w, compat_w, HH, WH);
        k_mf_iter<<<grid, 128, 0, stream>>>(logits_d, guid_d, Qb_d, Qa_d, spatial_w, bilateral_w, compat_w, HH, WH);
    }

    // --- out = 0.5 * up(Q_down) ---
    k_upcombine<<<cdiv(NB * NCLS * HWf, 256), 256, 0, stream>>>(Qa_d, out);

    // --- full-res mean field (region A now free -> Qa_f) ---
    k_softmax8<<<cdiv(NB * HWf, 256), 256, 0, stream>>>(logits, Qa_f, HWf);
    {
        dim3 grid(WF / TSX, HF / TSY, NB);
        k_mf_iter<<<grid, 128, 0, stream>>>(logits, guid, Qa_f, Qb_f, spatial_w, bilateral_w, compat_w, HF, WF);
        k_mf_iter<<<grid, 128, 0, stream>>>(logits, guid, Qb_f, Qa_f, spatial_w, bilateral_w, compat_w, HF, WF);
    }

    // --- out += 0.5 * Q_full ---
    k_addhalf<<<cdiv(NB * NCLS * HWf / 4, 256), 256, 0, stream>>>(
        (const float4*)Qa_f, (float4*)out, NB * NCLS * HWf / 4);
}

// Round 2
// 521.703 us; speedup vs baseline: 1.3991x; 1.3991x over previous
//
#include <hip/hip_runtime.h>
#include <math.h>

#define NB 8
#define NCLS 8
#define NGU 6
#define NBI 14
#define HF 512
#define WF 512
#define HH 256
#define WH 256

// mean-field tile params: 32x32 output tile, 256 threads, 2x2 px/thread
#define TSX 32
#define TSY 32
#define TPX 34
#define TPY 34
#define HALO (TPY * TPX)  // 1156

static __device__ __forceinline__ void ac_prep(int o, float scale, int insz,
                                               int& i0, int& i1, float& f) {
    float s = (float)o * scale;
    int ii = (int)floorf(s);
    if (ii > insz - 1) ii = insz - 1;
    if (ii < 0) ii = 0;
    i0 = ii;
    i1 = (ii + 1 < insz) ? (ii + 1) : (insz - 1);
    f = s - (float)ii;
}

// ---------------- K0: fill p buffers with bias ----------------
__global__ void k_fill_bias(float* __restrict__ out, const float* __restrict__ b, int HW) {
    int total = NB * 3 * HW;
    int idx = blockIdx.x * blockDim.x + threadIdx.x;
    if (idx >= total) return;
    int o = (idx / HW) % 3;
    out[idx] = b[o];
}

// ---------------- K1: skip 1x1 projection (channel-chunked, atomic) ----------------
__global__ void k_skip_proj(const float* __restrict__ feat, const float* __restrict__ w,
                            float* __restrict__ out, int C, int HW, int nch) {
    __shared__ float sw[3 * 512];
    for (int i = threadIdx.x; i < 3 * C; i += blockDim.x) sw[i] = w[i];
    __syncthreads();
    int total = NB * HW * nch;
    for (int idx = blockIdx.x * blockDim.x + threadIdx.x; idx < total;
         idx += gridDim.x * blockDim.x) {
        int hw = idx % HW;
        int t = idx / HW;
        int ch = t % nch;
        int n = t / nch;
        int c0 = ch * 64;
        const float* fp = feat + ((size_t)n * C + c0) * HW + hw;
        float a0 = 0.f, a1 = 0.f, a2 = 0.f;
        #pragma unroll 8
        for (int c = 0; c < 64; ++c) {
            float v = fp[(size_t)c * HW];
            a0 = fmaf(sw[c0 + c], v, a0);
            a1 = fmaf(sw[C + c0 + c], v, a1);
            a2 = fmaf(sw[2 * C + c0 + c], v, a2);
        }
        float* op = out + (size_t)n * 3 * HW + hw;
        atomicAdd(&op[0], a0);
        atomicAdd(&op[HW], a1);
        atomicAdd(&op[2 * HW], a2);
    }
}

// ---------------- K2: fused (sum of 4 upsampled levels / 4) + guidance concat ----------------
__global__ void k_fused_guid(const float* __restrict__ image,
                             const float* __restrict__ p0, const float* __restrict__ p1,
                             const float* __restrict__ p2, const float* __restrict__ p3,
                             float* __restrict__ guid) {
    const int HW = HF * WF;
    int total = NB * HW;
    int idx = blockIdx.x * blockDim.x + threadIdx.x;
    if (idx >= total) return;
    int n = idx / HW, r = idx - n * HW;
    int y = r / WF, x = r - y * WF;

    const float* ps[4] = {p0, p1, p2, p3};
    const int ss[4] = {256, 128, 64, 32};
    float f[3] = {0.f, 0.f, 0.f};
    #pragma unroll
    for (int l = 0; l < 4; ++l) {
        int s = ss[l];
        float scale = (float)(s - 1) / 511.0f;
        int y0, y1, x0, x1;
        float fy, fx;
        ac_prep(y, scale, s, y0, y1, fy);
        ac_prep(x, scale, s, x0, x1, fx);
        const float* pb = ps[l] + (size_t)n * 3 * s * s;
        #pragma unroll
        for (int o = 0; o < 3; ++o) {
            const float* pp = pb + (size_t)o * s * s;
            float v00 = pp[y0 * s + x0], v01 = pp[y0 * s + x1];
            float v10 = pp[y1 * s + x0], v11 = pp[y1 * s + x1];
            float r0 = v00 * (1.f - fy) + v10 * fy;
            float r1 = v01 * (1.f - fy) + v11 * fy;
            f[o] += r0 * (1.f - fx) + r1 * fx;
        }
    }
    float* gp = guid + (size_t)n * NGU * HW + y * WF + x;
    const float* ip = image + (size_t)n * 3 * HW + y * WF + x;
    #pragma unroll
    for (int o = 0; o < 3; ++o) gp[(size_t)o * HW] = ip[(size_t)o * HW];
    #pragma unroll
    for (int o = 0; o < 3; ++o) gp[(size_t)(3 + o) * HW] = f[o] * 0.25f;
}

// ---------------- K3: generic align-corners bilinear resize ----------------
__global__ void k_resize(const float* __restrict__ in, float* __restrict__ out,
                         int NCtot, int Hi, int Wi, int Ho, int Wo) {
    int total = NCtot * Ho * Wo;
    int idx = blockIdx.x * blockDim.x + threadIdx.x;
    if (idx >= total) return;
    float sy = (float)(Hi - 1) / (float)(Ho - 1);
    float sx = (float)(Wi - 1) / (float)(Wo - 1);
    int nc = idx / (Ho * Wo), r = idx - nc * (Ho * Wo);
    int yo = r / Wo, xo = r - yo * Wo;
    int y0, y1, x0, x1;
    float fy, fx;
    ac_prep(yo, sy, Hi, y0, y1, fy);
    ac_prep(xo, sx, Wi, x0, x1, fx);
    const float* ip = in + (size_t)nc * Hi * Wi;
    float v00 = ip[y0 * Wi + x0], v01 = ip[y0 * Wi + x1];
    float v10 = ip[y1 * Wi + x0], v11 = ip[y1 * Wi + x1];
    float r0 = v00 * (1.f - fy) + v10 * fy;
    float r1 = v01 * (1.f - fy) + v11 * fy;
    out[idx] = r0 * (1.f - fx) + r1 * fx;
}

// ---------------- K_prep: fold compat into conv weights ----------------
// W2[ci][tap][o] = sum_c cw[o,c]*wbil[c,ci,tap] + (ci<8 ? cw[o,ci]*wsp[ci,tap] : 0)
__global__ void k_prep_w(const float* __restrict__ wsp, const float* __restrict__ wbil,
                         const float* __restrict__ cw, float* __restrict__ W2) {
    int i = blockIdx.x * blockDim.x + threadIdx.x;
    if (i >= NBI * 9 * 8) return;
    int o = i & 7;
    int t = (i >> 3) % 9;
    int ci = i / 72;
    float s = 0.f;
    for (int c = 0; c < NCLS; ++c)
        s += cw[o * NCLS + c] * wbil[((size_t)c * NBI + ci) * 9 + t];
    if (ci < NCLS) s += cw[o * NCLS + ci] * wsp[ci * 9 + t];
    W2[ci * 72 + t * 8 + o] = s;
}

// ---------------- K5: one mean-field iteration ----------------
// FIRST: compute Q = softmax(unary) on the fly during staging (no Qin buffer)
// ACCUM: Qout[i] += 0.5 * q  (final full-res iteration folds into output)
template <bool FIRST, bool ACCUM>
__global__ __launch_bounds__(256) void k_mf(
    const float* __restrict__ unary, const float* __restrict__ guid,
    const float* __restrict__ Qin, float* __restrict__ Qout,
    const float* __restrict__ W2, int H, int W) {
    __shared__ float s_tile[NBI * HALO];  // 14*34*34*4 = 64736 B

    const int tid = threadIdx.x;
    const int n = blockIdx.z;
    const int bx = blockIdx.x * TSX;
    const int by = blockIdx.y * TSY;
    const int HW = H * W;
    const int y0 = by - 1, x0 = bx - 1;

    // stage guidance channels (8..13)
    for (int i = tid; i < NGU * HALO; i += 256) {
        int ch = i / HALO;
        int r = i - ch * HALO;
        int yy = r / TPX, xx = r - yy * TPX;
        int gy = y0 + yy, gx = x0 + xx;
        float v = 0.f;
        if ((unsigned)gy < (unsigned)H && (unsigned)gx < (unsigned)W)
            v = guid[((size_t)n * NGU + ch) * HW + gy * W + gx];
        s_tile[(NCLS + ch) * HALO + r] = v;
    }
    // stage Q channels (0..7)
    if (FIRST) {
        for (int i = tid; i < HALO; i += 256) {
            int yy = i / TPX, xx = i - yy * TPX;
            int gy = y0 + yy, gx = x0 + xx;
            if ((unsigned)gy < (unsigned)H && (unsigned)gx < (unsigned)W) {
                const float* up = unary + (size_t)n * NCLS * HW + gy * W + gx;
                float u[8];
                #pragma unroll
                for (int o = 0; o < 8; ++o) u[o] = up[(size_t)o * HW];
                float mx = u[0];
                #pragma unroll
                for (int o = 1; o < 8; ++o) mx = fmaxf(mx, u[o]);
                float s = 0.f;
                #pragma unroll
                for (int o = 0; o < 8; ++o) { u[o] = __expf(u[o] - mx); s += u[o]; }
                float inv = 1.f / s;
                #pragma unroll
                for (int o = 0; o < 8; ++o) s_tile[o * HALO + i] = u[o] * inv;
            } else {
                #pragma unroll
                for (int o = 0; o < 8; ++o) s_tile[o * HALO + i] = 0.f;
            }
        }
    } else {
        for (int i = tid; i < NCLS * HALO; i += 256) {
            int ch = i / HALO;
            int r = i - ch * HALO;
            int yy = r / TPX, xx = r - yy * TPX;
            int gy = y0 + yy, gx = x0 + xx;
            float v = 0.f;
            if ((unsigned)gy < (unsigned)H && (unsigned)gx < (unsigned)W)
                v = Qin[((size_t)n * NCLS + ch) * HW + gy * W + gx];
            s_tile[i] = v;
        }
    }
    __syncthreads();

    const int tx = tid & 15;
    const int ty = tid >> 4;

    float acc[2][2][8];
    #pragma unroll
    for (int a = 0; a < 2; ++a)
        #pragma unroll
        for (int b = 0; b < 2; ++b)
            #pragma unroll
            for (int o = 0; o < 8; ++o) acc[a][b][o] = 0.f;

    const float* tbase = &s_tile[(2 * ty) * TPX + 2 * tx];

    #pragma unroll 2
    for (int ci = 0; ci < NBI; ++ci) {
        // 4x4 pixel patch via float2 LDS reads (8B aligned)
        float v[4][4];
        const float* tp = tbase + ci * HALO;
        #pragma unroll
        for (int r = 0; r < 4; ++r) {
            float2 pa = *reinterpret_cast<const float2*>(&tp[r * TPX]);
            float2 pb = *reinterpret_cast<const float2*>(&tp[r * TPX + 2]);
            v[r][0] = pa.x; v[r][1] = pa.y; v[r][2] = pb.x; v[r][3] = pb.y;
        }
        // weights: wave-uniform scalar loads (s_load), zero LDS traffic
        const float* wp = W2 + ci * 72;
        #pragma unroll
        for (int ky = 0; ky < 3; ++ky) {
            #pragma unroll
            for (int kx = 0; kx < 3; ++kx) {
                const float* w8 = wp + (ky * 3 + kx) * 8;
                #pragma unroll
                for (int o = 0; o < 8; ++o) {
                    const float w = w8[o];
                    acc[0][0][o] = fmaf(w, v[ky][kx], acc[0][0][o]);
                    acc[0][1][o] = fmaf(w, v[ky][kx + 1], acc[0][1][o]);
                    acc[1][0][o] = fmaf(w, v[ky + 1][kx], acc[1][0][o]);
                    acc[1][1][o] = fmaf(w, v[ky + 1][kx + 1], acc[1][1][o]);
                }
            }
        }
    }

    // epilogue: u = unary - message ; softmax ; write (or accumulate 0.5*)
    #pragma unroll
    for (int a = 0; a < 2; ++a) {
        const int y = by + 2 * ty + a;
        const size_t rowoff = (size_t)n * NCLS * HW + (size_t)y * W + (bx + 2 * tx);
        float2 u2[8];
        #pragma unroll
        for (int o = 0; o < 8; ++o)
            u2[o] = *reinterpret_cast<const float2*>(&unary[rowoff + (size_t)o * HW]);
        float q0[8], q1[8];
        float m0 = -1e30f, m1 = -1e30f;
        #pragma unroll
        for (int o = 0; o < 8; ++o) {
            q0[o] = u2[o].x - acc[a][0][o];
            q1[o] = u2[o].y - acc[a][1][o];
            m0 = fmaxf(m0, q0[o]);
            m1 = fmaxf(m1, q1[o]);
        }
        float s0 = 0.f, s1 = 0.f;
        #pragma unroll
        for (int o = 0; o < 8; ++o) {
            q0[o] = __expf(q0[o] - m0); s0 += q0[o];
            q1[o] = __expf(q1[o] - m1); s1 += q1[o];
        }
        const float i0 = 1.f / s0, i1 = 1.f / s1;
        #pragma unroll
        for (int o = 0; o < 8; ++o) {
            float2 qv;
            qv.x = q0[o] * i0;
            qv.y = q1[o] * i1;
            float2* op = reinterpret_cast<float2*>(&Qout[rowoff + (size_t)o * HW]);
            if (ACCUM) {
                float2 cur = *op;
                cur.x = fmaf(0.5f, qv.x, cur.x);
                cur.y = fmaf(0.5f, qv.y, cur.y);
                *op = cur;
            } else {
                *op = qv;
            }
        }
    }
}

// ---------------- K6: out = 0.5 * upsample(Q_down) ----------------
__global__ void k_upcombine(const float* __restrict__ Qd, float* __restrict__ out) {
    const int HW = HF * WF;
    int total = NB * NCLS * HW;
    int idx = blockIdx.x * blockDim.x + threadIdx.x;
    if (idx >= total) return;
    int nc = idx / HW, r = idx - nc * HW;
    int y = r / WF, x = r - y * WF;
    const float sc = 255.f / 511.f;
    int y0, y1, x0, x1;
    float fy, fx;
    ac_prep(y, sc, HH, y0, y1, fy);
    ac_prep(x, sc, WH, x0, x1, fx);
    const float* qp = Qd + (size_t)nc * (HH * WH);
    float v00 = qp[y0 * WH + x0], v01 = qp[y0 * WH + x1];
    float v10 = qp[y1 * WH + x0], v11 = qp[y1 * WH + x1];
    float r0 = v00 * (1.f - fy) + v10 * fy;
    float r1 = v01 * (1.f - fy) + v11 * fy;
    out[idx] = 0.5f * (r0 * (1.f - fx) + r1 * fx);
}

static inline int cdiv(int a, int b) { return (a + b - 1) / b; }

extern "C" void kernel_launch(void* const* d_in, const int* in_sizes, int n_in,
                              void* d_out, int out_size, void* d_ws, size_t ws_size,
                              hipStream_t stream) {
    const float* logits = (const float*)d_in[0];
    const float* image = (const float*)d_in[1];
    const float* skip0 = (const float*)d_in[2];
    const float* skip1 = (const float*)d_in[3];
    const float* skip2 = (const float*)d_in[4];
    const float* skip3 = (const float*)d_in[5];
    const float* spatial_w = (const float*)d_in[6];
    const float* bilateral_w = (const float*)d_in[7];
    const float* compat_w = (const float*)d_in[8];
    const float* skip_w0 = (const float*)d_in[9];
    const float* skip_b0 = (const float*)d_in[10];
    const float* skip_w1 = (const float*)d_in[11];
    const float* skip_b1 = (const float*)d_in[12];
    const float* skip_w2 = (const float*)d_in[13];
    const float* skip_b2 = (const float*)d_in[14];
    const float* skip_w3 = (const float*)d_in[15];
    const float* skip_b3 = (const float*)d_in[16];
    float* out = (float*)d_out;
    float* ws = (float*)d_ws;

    // workspace layout (floats). Region A is time-shared:
    //  phase 1: p0..p3 ; phase 2 (after guid built): logits_d/guid_d/Qa_d/Qb_d
    float* p0 = ws + 0;
    float* p1 = p0 + (size_t)NB * 3 * 256 * 256;
    float* p2 = p1 + (size_t)NB * 3 * 128 * 128;
    float* p3 = p2 + (size_t)NB * 3 * 64 * 64;
    float* logits_d = ws + 0;
    float* guid_d = ws + 4194304;
    float* Qa_d = ws + 7340032;
    float* Qb_d = ws + 11534336;
    float* W2 = ws + 16000000;      // 1008 floats in the gap before guid
    float* guid = ws + 16777216;
    float* Qb_f = ws + 29360128;

    const int HWf = HF * WF;   // 262144
    const int HWh = HH * WH;   // 65536

    // --- fold compat matrix into conv weights ---
    k_prep_w<<<4, 256, 0, stream>>>(spatial_w, bilateral_w, compat_w, W2);

    // --- skip projections ---
    k_fill_bias<<<cdiv(NB * 3 * 65536, 256), 256, 0, stream>>>(p0, skip_b0, 65536);
    k_fill_bias<<<cdiv(NB * 3 * 16384, 256), 256, 0, stream>>>(p1, skip_b1, 16384);
    k_fill_bias<<<cdiv(NB * 3 * 4096, 256), 256, 0, stream>>>(p2, skip_b2, 4096);
    k_fill_bias<<<cdiv(NB * 3 * 1024, 256), 256, 0, stream>>>(p3, skip_b3, 1024);

    k_skip_proj<<<cdiv(NB * 65536 * 1, 256), 256, 0, stream>>>(skip0, skip_w0, p0, 64, 65536, 1);
    k_skip_proj<<<cdiv(NB * 16384 * 2, 256), 256, 0, stream>>>(skip1, skip_w1, p1, 128, 16384, 2);
    k_skip_proj<<<cdiv(NB * 4096 * 4, 256), 256, 0, stream>>>(skip2, skip_w2, p2, 256, 4096, 4);
    k_skip_proj<<<cdiv(NB * 1024 * 8, 256), 256, 0, stream>>>(skip3, skip_w3, p3, 512, 1024, 8);

    // --- fused + guidance ---
    k_fused_guid<<<cdiv(NB * HWf, 256), 256, 0, stream>>>(image, p0, p1, p2, p3, guid);

    // --- downsample logits & guidance ---
    k_resize<<<cdiv(NB * NCLS * HWh, 256), 256, 0, stream>>>(logits, logits_d, NB * NCLS, HF, WF, HH, WH);
    k_resize<<<cdiv(NB * NGU * HWh, 256), 256, 0, stream>>>(guid, guid_d, NB * NGU, HF, WF, HH, WH);

    // --- half-res mean field (softmax fused into first iter) ---
    {
        dim3 grid(WH / TSX, HH / TSY, NB);
        k_mf<true, false><<<grid, 256, 0, stream>>>(logits_d, guid_d, nullptr, Qb_d, W2, HH, WH);
        k_mf<false, false><<<grid, 256, 0, stream>>>(logits_d, guid_d, Qb_d, Qa_d, W2, HH, WH);
    }

    // --- out = 0.5 * up(Q_down) ---
    k_upcombine<<<cdiv(NB * NCLS * HWf, 256), 256, 0, stream>>>(Qa_d, out);

    // --- full-res mean field; last iter accumulates 0.5*Q into out ---
    {
        dim3 grid(WF / TSX, HF / TSY, NB);
        k_mf<true, false><<<grid, 256, 0, stream>>>(logits, guid, nullptr, Qb_f, W2, HF, WF);
        k_mf<false, true><<<grid, 256, 0, stream>>>(logits, guid, Qb_f, out, W2, HF, WF);
    }
}

// Round 3
// 412.742 us; speedup vs baseline: 1.7685x; 1.2640x over previous
//
#include <hip/hip_runtime.h>
#include <hip/hip_fp16.h>
#include <math.h>

#define NB 8
#define NCLS 8
#define NGU 6
#define NBI 14
#define HF 512
#define WF 512
#define HH 256
#define WH 256

// fused mean-field tile: 32x32 output, 36x36 staging halo (2 iterations)
#define S2 36
#define RS 40                 // LDS row stride in halves (bank-friendly, even)
#define CS (S2 * RS)          // channel stride in halves (1440)
#define LDH (NBI * CS)        // 20160 halves = 40320 B

typedef float v2f __attribute__((ext_vector_type(2)));

static __device__ __forceinline__ void ac_prep(int o, float scale, int insz,
                                               int& i0, int& i1, float& f) {
    float s = (float)o * scale;
    int ii = (int)floorf(s);
    if (ii > insz - 1) ii = insz - 1;
    if (ii < 0) ii = 0;
    i0 = ii;
    i1 = (ii + 1 < insz) ? (ii + 1) : (insz - 1);
    f = s - (float)ii;
}

// ---------------- K0: fill p buffers with bias ----------------
__global__ void k_fill_bias(float* __restrict__ out, const float* __restrict__ b, int HW) {
    int total = NB * 3 * HW;
    int idx = blockIdx.x * blockDim.x + threadIdx.x;
    if (idx >= total) return;
    int o = (idx / HW) % 3;
    out[idx] = b[o];
}

// ---------------- K1: skip 1x1 projection (channel-chunked, atomic) ----------------
__global__ void k_skip_proj(const float* __restrict__ feat, const float* __restrict__ w,
                            float* __restrict__ out, int C, int HW, int nch) {
    __shared__ float sw[3 * 512];
    for (int i = threadIdx.x; i < 3 * C; i += blockDim.x) sw[i] = w[i];
    __syncthreads();
    int total = NB * HW * nch;
    for (int idx = blockIdx.x * blockDim.x + threadIdx.x; idx < total;
         idx += gridDim.x * blockDim.x) {
        int hw = idx % HW;
        int t = idx / HW;
        int ch = t % nch;
        int n = t / nch;
        int c0 = ch * 64;
        const float* fp = feat + ((size_t)n * C + c0) * HW + hw;
        float a0 = 0.f, a1 = 0.f, a2 = 0.f;
        #pragma unroll 8
        for (int c = 0; c < 64; ++c) {
            float v = fp[(size_t)c * HW];
            a0 = fmaf(sw[c0 + c], v, a0);
            a1 = fmaf(sw[C + c0 + c], v, a1);
            a2 = fmaf(sw[2 * C + c0 + c], v, a2);
        }
        float* op = out + (size_t)n * 3 * HW + hw;
        atomicAdd(&op[0], a0);
        atomicAdd(&op[HW], a1);
        atomicAdd(&op[2 * HW], a2);
    }
}

// ---------------- K2: fused (sum of 4 upsampled levels / 4) + guidance concat ----------------
__global__ void k_fused_guid(const float* __restrict__ image,
                             const float* __restrict__ p0, const float* __restrict__ p1,
                             const float* __restrict__ p2, const float* __restrict__ p3,
                             float* __restrict__ guid) {
    const int HW = HF * WF;
    int total = NB * HW;
    int idx = blockIdx.x * blockDim.x + threadIdx.x;
    if (idx >= total) return;
    int n = idx / HW, r = idx - n * HW;
    int y = r / WF, x = r - y * WF;

    const float* ps[4] = {p0, p1, p2, p3};
    const int ss[4] = {256, 128, 64, 32};
    float f[3] = {0.f, 0.f, 0.f};
    #pragma unroll
    for (int l = 0; l < 4; ++l) {
        int s = ss[l];
        float scale = (float)(s - 1) / 511.0f;
        int y0, y1, x0, x1;
        float fy, fx;
        ac_prep(y, scale, s, y0, y1, fy);
        ac_prep(x, scale, s, x0, x1, fx);
        const float* pb = ps[l] + (size_t)n * 3 * s * s;
        #pragma unroll
        for (int o = 0; o < 3; ++o) {
            const float* pp = pb + (size_t)o * s * s;
            float v00 = pp[y0 * s + x0], v01 = pp[y0 * s + x1];
            float v10 = pp[y1 * s + x0], v11 = pp[y1 * s + x1];
            float r0 = v00 * (1.f - fy) + v10 * fy;
            float r1 = v01 * (1.f - fy) + v11 * fy;
            f[o] += r0 * (1.f - fx) + r1 * fx;
        }
    }
    float* gp = guid + (size_t)n * NGU * HW + y * WF + x;
    const float* ip = image + (size_t)n * 3 * HW + y * WF + x;
    #pragma unroll
    for (int o = 0; o < 3; ++o) gp[(size_t)o * HW] = ip[(size_t)o * HW];
    #pragma unroll
    for (int o = 0; o < 3; ++o) gp[(size_t)(3 + o) * HW] = f[o] * 0.25f;
}

// ---------------- K3: generic align-corners bilinear resize ----------------
__global__ void k_resize(const float* __restrict__ in, float* __restrict__ out,
                         int NCtot, int Hi, int Wi, int Ho, int Wo) {
    int total = NCtot * Ho * Wo;
    int idx = blockIdx.x * blockDim.x + threadIdx.x;
    if (idx >= total) return;
    float sy = (float)(Hi - 1) / (float)(Ho - 1);
    float sx = (float)(Wi - 1) / (float)(Wo - 1);
    int nc = idx / (Ho * Wo), r = idx - nc * (Ho * Wo);
    int yo = r / Wo, xo = r - yo * Wo;
    int y0, y1, x0, x1;
    float fy, fx;
    ac_prep(yo, sy, Hi, y0, y1, fy);
    ac_prep(xo, sx, Wi, x0, x1, fx);
    const float* ip = in + (size_t)nc * Hi * Wi;
    float v00 = ip[y0 * Wi + x0], v01 = ip[y0 * Wi + x1];
    float v10 = ip[y1 * Wi + x0], v11 = ip[y1 * Wi + x1];
    float r0 = v00 * (1.f - fy) + v10 * fy;
    float r1 = v01 * (1.f - fy) + v11 * fy;
    out[idx] = r0 * (1.f - fx) + r1 * fx;
}

// ---------------- K_prep: fold compat into conv weights ----------------
// W2[ci][tap][o] = sum_c cw[o,c]*wbil[c,ci,tap] + (ci<8 ? cw[o,ci]*wsp[ci,tap] : 0)
__global__ void k_prep_w(const float* __restrict__ wsp, const float* __restrict__ wbil,
                         const float* __restrict__ cw, float* __restrict__ W2) {
    int i = blockIdx.x * blockDim.x + threadIdx.x;
    if (i >= NBI * 9 * 8) return;
    int o = i & 7;
    int t = (i >> 3) % 9;
    int ci = i / 72;
    float s = 0.f;
    for (int c = 0; c < NCLS; ++c)
        s += cw[o * NCLS + c] * wbil[((size_t)c * NBI + ci) * 9 + t];
    if (ci < NCLS) s += cw[o * NCLS + ci] * wsp[ci * 9 + t];
    W2[ci * 72 + t * 8 + o] = s;
}

// ---------------- K5: BOTH mean-field iterations fused, fp16 LDS tile ----------------
// Q0 = softmax(unary) computed during staging (36x36 halo, zero-padded).
// iter1 -> Q1 on 34x34 interior (held in regs across barrier, written in place).
// iter2 -> 32x32 output; ACCUM: Qout += 0.5*q.
template <bool ACCUM>
__global__ __launch_bounds__(256, 4) void k_mf2(
    const float* __restrict__ unary, const float* __restrict__ guid,
    float* __restrict__ Qout, const float* __restrict__ W2, int H, int W) {
    __shared__ __half s_t[LDH];  // 40320 B -> 4 blocks/CU

    const int tid = threadIdx.x;
    const int n = blockIdx.z;
    const int bx = blockIdx.x * 32;
    const int by = blockIdx.y * 32;
    const int HW = H * W;
    const int y0 = by - 2, x0 = bx - 2;
    const float* ubase = unary + (size_t)n * NCLS * HW;
    const float* gbase = guid + (size_t)n * NGU * HW;

    // ---- stage guidance channels (8..13), zero-padded ----
    for (int i = tid; i < NGU * S2 * S2; i += 256) {
        int ch = i / (S2 * S2);
        int r = i - ch * (S2 * S2);
        int yy = r / S2, xx = r - yy * S2;
        int gy = y0 + yy, gx = x0 + xx;
        float v = 0.f;
        if ((unsigned)gy < (unsigned)H && (unsigned)gx < (unsigned)W)
            v = gbase[(size_t)ch * HW + (size_t)gy * W + gx];
        s_t[(NCLS + ch) * CS + yy * RS + xx] = __float2half(v);
    }
    // ---- stage Q0 = softmax(unary), zero-padded ----
    for (int i = tid; i < S2 * S2; i += 256) {
        int yy = i / S2, xx = i - yy * S2;
        int gy = y0 + yy, gx = x0 + xx;
        if ((unsigned)gy < (unsigned)H && (unsigned)gx < (unsigned)W) {
            const float* up = ubase + (size_t)gy * W + gx;
            float u[8];
            #pragma unroll
            for (int o = 0; o < 8; ++o) u[o] = up[(size_t)o * HW];
            float mx = u[0];
            #pragma unroll
            for (int o = 1; o < 8; ++o) mx = fmaxf(mx, u[o]);
            float s = 0.f;
            #pragma unroll
            for (int o = 0; o < 8; ++o) { u[o] = __expf(u[o] - mx); s += u[o]; }
            float inv = 1.f / s;
            #pragma unroll
            for (int o = 0; o < 8; ++o)
                s_t[o * CS + yy * RS + xx] = __float2half(u[o] * inv);
        } else {
            #pragma unroll
            for (int o = 0; o < 8; ++o) s_t[o * CS + yy * RS + xx] = __float2half(0.f);
        }
    }
    __syncthreads();

    // ---- iter 1: Q1 over 34x34 interior (staging coords 1..34) ----
    // units: 17x17 of 2x2 px; thread handles units tid and tid+256
    __half2 hq[2][16];  // [unit][a*8+o], packs (b=0,b=1)
    #pragma unroll
    for (int u2 = 0; u2 < 2; ++u2) {
        const int u = tid + 256 * u2;
        const bool act = (u < 289);
        if (act) {
            const int uy = u / 17, ux = u - uy * 17;
            v2f acc1[2][8];
            #pragma unroll
            for (int a = 0; a < 2; ++a)
                #pragma unroll
                for (int o = 0; o < 8; ++o) acc1[a][o] = (v2f){0.f, 0.f};

            for (int ci = 0; ci < NBI; ++ci) {
                const __half2* tp =
                    (const __half2*)(s_t + ci * CS + (2 * uy) * RS + 2 * ux);
                v2f pv[4][3];
                #pragma unroll
                for (int r = 0; r < 4; ++r) {
                    float2 aa = __half22float2(tp[r * (RS / 2)]);
                    float2 bb = __half22float2(tp[r * (RS / 2) + 1]);
                    pv[r][0] = (v2f){aa.x, aa.y};
                    pv[r][1] = (v2f){aa.y, bb.x};
                    pv[r][2] = (v2f){bb.x, bb.y};
                }
                const float* wp = W2 + ci * 72;
                #pragma unroll
                for (int ky = 0; ky < 3; ++ky) {
                    #pragma unroll
                    for (int kx = 0; kx < 3; ++kx) {
                        const float* w8 = wp + (ky * 3 + kx) * 8;
                        #pragma unroll
                        for (int o = 0; o < 8; ++o) {
                            const float w = w8[o];
                            v2f ws = (v2f){w, w};
                            acc1[0][o] = __builtin_elementwise_fma(ws, pv[ky][kx], acc1[0][o]);
                            acc1[1][o] = __builtin_elementwise_fma(ws, pv[1 + ky][kx], acc1[1][o]);
                        }
                    }
                }
            }
            // epilogue: q = softmax(unary - msg); OOB px -> 0
            const int ybase = by - 1 + 2 * uy;
            const int xb = bx - 1 + 2 * ux;
            #pragma unroll
            for (int a = 0; a < 2; ++a) {
                const int y = ybase + a;
                float qq[2][8];
                #pragma unroll
                for (int b = 0; b < 2; ++b) {
                    const int x = xb + b;
                    if ((unsigned)y < (unsigned)H && (unsigned)x < (unsigned)W) {
                        const float* up = ubase + (size_t)y * W + x;
                        float q[8];
                        float mx = -1e30f;
                        #pragma unroll
                        for (int o = 0; o < 8; ++o) {
                            float m = b ? acc1[a][o].y : acc1[a][o].x;
                            q[o] = up[(size_t)o * HW] - m;
                            mx = fmaxf(mx, q[o]);
                        }
                        float s = 0.f;
                        #pragma unroll
                        for (int o = 0; o < 8; ++o) { q[o] = __expf(q[o] - mx); s += q[o]; }
                        float inv = 1.f / s;
                        #pragma unroll
                        for (int o = 0; o < 8; ++o) qq[b][o] = q[o] * inv;
                    } else {
                        #pragma unroll
                        for (int o = 0; o < 8; ++o) qq[b][o] = 0.f;
                    }
                }
                #pragma unroll
                for (int o = 0; o < 8; ++o)
                    hq[u2][a * 8 + o] =
                        __halves2half2(__float2half(qq[0][o]), __float2half(qq[1][o]));
            }
        }
    }
    __syncthreads();
    // write Q1 back in place (interior only; ring rows/cols 0,35 unused by iter2)
    #pragma unroll
    for (int u2 = 0; u2 < 2; ++u2) {
        const int u = tid + 256 * u2;
        if (u < 289) {
            const int uy = u / 17, ux = u - uy * 17;
            #pragma unroll
            for (int a = 0; a < 2; ++a) {
                const int row = (1 + 2 * uy + a) * RS + (1 + 2 * ux);
                #pragma unroll
                for (int o = 0; o < 8; ++o) {
                    s_t[o * CS + row] = __low2half(hq[u2][a * 8 + o]);
                    s_t[o * CS + row + 1] = __high2half(hq[u2][a * 8 + o]);
                }
            }
        }
    }
    __syncthreads();

    // ---- iter 2: 32x32 output (staging coords 2..33) ----
    {
        const int tx = tid & 15, ty = tid >> 4;
        v2f acc[2][8];
        #pragma unroll
        for (int a = 0; a < 2; ++a)
            #pragma unroll
            for (int o = 0; o < 8; ++o) acc[a][o] = (v2f){0.f, 0.f};

        for (int ci = 0; ci < NBI; ++ci) {
            const __half2* tp =
                (const __half2*)(s_t + ci * CS + (1 + 2 * ty) * RS + 2 * tx);
            v2f pv[4][3];
            #pragma unroll
            for (int r = 0; r < 4; ++r) {
                float2 aa = __half22float2(tp[r * (RS / 2)]);
                float2 bb = __half22float2(tp[r * (RS / 2) + 1]);
                float2 cc = __half22float2(tp[r * (RS / 2) + 2]);
                pv[r][0] = (v2f){aa.y, bb.x};
                pv[r][1] = (v2f){bb.x, bb.y};
                pv[r][2] = (v2f){bb.y, cc.x};
            }
            const float* wp = W2 + ci * 72;
            #pragma unroll
            for (int ky = 0; ky < 3; ++ky) {
                #pragma unroll
                for (int kx = 0; kx < 3; ++kx) {
                    const float* w8 = wp + (ky * 3 + kx) * 8;
                    #pragma unroll
                    for (int o = 0; o < 8; ++o) {
                        const float w = w8[o];
                        v2f ws = (v2f){w, w};
                        acc[0][o] = __builtin_elementwise_fma(ws, pv[ky][kx], acc[0][o]);
                        acc[1][o] = __builtin_elementwise_fma(ws, pv[1 + ky][kx], acc[1][o]);
                    }
                }
            }
        }
        // epilogue (all px in-image)
        float* qbase = Qout + (size_t)n * NCLS * HW;
        #pragma unroll
        for (int a = 0; a < 2; ++a) {
            const int y = by + 2 * ty + a;
            const size_t rowoff = (size_t)y * W + (bx + 2 * tx);
            float q0[8], q1[8];
            float m0 = -1e30f, m1 = -1e30f;
            #pragma unroll
            for (int o = 0; o < 8; ++o) {
                float2 uv = *reinterpret_cast<const float2*>(&ubase[(size_t)o * HW + rowoff]);
                q0[o] = uv.x - acc[a][o].x;
                q1[o] = uv.y - acc[a][o].y;
                m0 = fmaxf(m0, q0[o]);
                m1 = fmaxf(m1, q1[o]);
            }
            float s0 = 0.f, s1 = 0.f;
            #pragma unroll
            for (int o = 0; o < 8; ++o) {
                q0[o] = __expf(q0[o] - m0); s0 += q0[o];
                q1[o] = __expf(q1[o] - m1); s1 += q1[o];
            }
            const float i0 = 1.f / s0, i1 = 1.f / s1;
            #pragma unroll
            for (int o = 0; o < 8; ++o) {
                float2 qv;
                qv.x = q0[o] * i0;
                qv.y = q1[o] * i1;
                float2* op = reinterpret_cast<float2*>(&qbase[(size_t)o * HW + rowoff]);
                if (ACCUM) {
                    float2 cur = *op;
                    cur.x = fmaf(0.5f, qv.x, cur.x);
                    cur.y = fmaf(0.5f, qv.y, cur.y);
                    *op = cur;
                } else {
                    *op = qv;
                }
            }
        }
    }
}

// ---------------- K6: out = 0.5 * upsample(Q_down) ----------------
__global__ void k_upcombine(const float* __restrict__ Qd, float* __restrict__ out) {
    const int HW = HF * WF;
    int total = NB * NCLS * HW;
    int idx = blockIdx.x * blockDim.x + threadIdx.x;
    if (idx >= total) return;
    int nc = idx / HW, r = idx - nc * HW;
    int y = r / WF, x = r - y * WF;
    const float sc = 255.f / 511.f;
    int y0, y1, x0, x1;
    float fy, fx;
    ac_prep(y, sc, HH, y0, y1, fy);
    ac_prep(x, sc, WH, x0, x1, fx);
    const float* qp = Qd + (size_t)nc * (HH * WH);
    float v00 = qp[y0 * WH + x0], v01 = qp[y0 * WH + x1];
    float v10 = qp[y1 * WH + x0], v11 = qp[y1 * WH + x1];
    float r0 = v00 * (1.f - fy) + v10 * fy;
    float r1 = v01 * (1.f - fy) + v11 * fy;
    out[idx] = 0.5f * (r0 * (1.f - fx) + r1 * fx);
}

static inline int cdiv(int a, int b) { return (a + b - 1) / b; }

extern "C" void kernel_launch(void* const* d_in, const int* in_sizes, int n_in,
                              void* d_out, int out_size, void* d_ws, size_t ws_size,
                              hipStream_t stream) {
    const float* logits = (const float*)d_in[0];
    const float* image = (const float*)d_in[1];
    const float* skip0 = (const float*)d_in[2];
    const float* skip1 = (const float*)d_in[3];
    const float* skip2 = (const float*)d_in[4];
    const float* skip3 = (const float*)d_in[5];
    const float* spatial_w = (const float*)d_in[6];
    const float* bilateral_w = (const float*)d_in[7];
    const float* compat_w = (const float*)d_in[8];
    const float* skip_w0 = (const float*)d_in[9];
    const float* skip_b0 = (const float*)d_in[10];
    const float* skip_w1 = (const float*)d_in[11];
    const float* skip_b1 = (const float*)d_in[12];
    const float* skip_w2 = (const float*)d_in[13];
    const float* skip_b2 = (const float*)d_in[14];
    const float* skip_w3 = (const float*)d_in[15];
    const float* skip_b3 = (const float*)d_in[16];
    float* out = (float*)d_out;
    float* ws = (float*)d_ws;

    // workspace layout (floats). Region A time-shared:
    //  phase 1: p0..p3 ; phase 2 (after guid built): logits_d/guid_d/Qa_d
    float* p0 = ws + 0;
    float* p1 = p0 + (size_t)NB * 3 * 256 * 256;
    float* p2 = p1 + (size_t)NB * 3 * 128 * 128;
    float* p3 = p2 + (size_t)NB * 3 * 64 * 64;
    float* logits_d = ws + 0;
    float* guid_d = ws + 4194304;
    float* Qa_d = ws + 7340032;
    float* W2 = ws + 16000000;
    float* guid = ws + 16777216;

    const int HWf = HF * WF;
    const int HWh = HH * WH;

    // --- fold compat matrix into conv weights ---
    k_prep_w<<<4, 256, 0, stream>>>(spatial_w, bilateral_w, compat_w, W2);

    // --- skip projections ---
    k_fill_bias<<<cdiv(NB * 3 * 65536, 256), 256, 0, stream>>>(p0, skip_b0, 65536);
    k_fill_bias<<<cdiv(NB * 3 * 16384, 256), 256, 0, stream>>>(p1, skip_b1, 16384);
    k_fill_bias<<<cdiv(NB * 3 * 4096, 256), 256, 0, stream>>>(p2, skip_b2, 4096);
    k_fill_bias<<<cdiv(NB * 3 * 1024, 256), 256, 0, stream>>>(p3, skip_b3, 1024);

    k_skip_proj<<<cdiv(NB * 65536 * 1, 256), 256, 0, stream>>>(skip0, skip_w0, p0, 64, 65536, 1);
    k_skip_proj<<<cdiv(NB * 16384 * 2, 256), 256, 0, stream>>>(skip1, skip_w1, p1, 128, 16384, 2);
    k_skip_proj<<<cdiv(NB * 4096 * 4, 256), 256, 0, stream>>>(skip2, skip_w2, p2, 256, 4096, 4);
    k_skip_proj<<<cdiv(NB * 1024 * 8, 256), 256, 0, stream>>>(skip3, skip_w3, p3, 512, 1024, 8);

    // --- fused + guidance ---
    k_fused_guid<<<cdiv(NB * HWf, 256), 256, 0, stream>>>(image, p0, p1, p2, p3, guid);

    // --- downsample logits & guidance ---
    k_resize<<<cdiv(NB * NCLS * HWh, 256), 256, 0, stream>>>(logits, logits_d, NB * NCLS, HF, WF, HH, WH);
    k_resize<<<cdiv(NB * NGU * HWh, 256), 256, 0, stream>>>(guid, guid_d, NB * NGU, HF, WF, HH, WH);

    // --- half-res mean field (both iterations fused) ---
    {
        dim3 grid(WH / 32, HH / 32, NB);
        k_mf2<false><<<grid, 256, 0, stream>>>(logits_d, guid_d, Qa_d, W2, HH, WH);
    }

    // --- out = 0.5 * up(Q_down) ---
    k_upcombine<<<cdiv(NB * NCLS * HWf, 256), 256, 0, stream>>>(Qa_d, out);

    // --- full-res mean field (fused), accumulating 0.5*Q into out ---
    {
        dim3 grid(WF / 32, HF / 32, NB);
        k_mf2<true><<<grid, 256, 0, stream>>>(logits, guid, out, W2, HF, WF);
    }
}

// Round 4
// 303.853 us; speedup vs baseline: 2.4022x; 1.3584x over previous
//
#include <hip/hip_runtime.h>
#include <hip/hip_fp16.h>
#include <math.h>

#define NB 8
#define NCLS 8
#define NGU 6
#define NBI 14
#define HF 512
#define WF 512
#define HH 256
#define WH 256

// MFMA mean-field tile: 32x16 output, 36x20 staged halo
#define TOX 32
#define TOY 16
#define SX 36
#define SY 20
#define SPX (SY * SX)     // 720 staged px
#define R1W 36
#define R1N (18 * 36)     // iter1 region: rows 1..18 x cols 0..35 = 648 px
#define R1T 41            // ceil(648/16)
#define R2N (TOX * TOY)   // 512
#define R2T 32

typedef _Float16 f16x8 __attribute__((ext_vector_type(8)));
typedef _Float16 f16x2 __attribute__((ext_vector_type(2)));
typedef float f32x4 __attribute__((ext_vector_type(4)));

static __device__ __forceinline__ void ac_prep(int o, float scale, int insz,
                                               int& i0, int& i1, float& f) {
    float s = (float)o * scale;
    int ii = (int)floorf(s);
    if (ii > insz - 1) ii = insz - 1;
    if (ii < 0) ii = 0;
    i0 = ii;
    i1 = (ii + 1 < insz) ? (ii + 1) : (insz - 1);
    f = s - (float)ii;
}

// ---------------- K0: fill p buffers with bias ----------------
__global__ void k_fill_bias(float* __restrict__ out, const float* __restrict__ b, int HW) {
    int total = NB * 3 * HW;
    int idx = blockIdx.x * blockDim.x + threadIdx.x;
    if (idx >= total) return;
    int o = (idx / HW) % 3;
    out[idx] = b[o];
}

// ---------------- K1: skip 1x1 projection (channel-chunked, atomic) ----------------
__global__ void k_skip_proj(const float* __restrict__ feat, const float* __restrict__ w,
                            float* __restrict__ out, int C, int HW, int nch) {
    __shared__ float sw[3 * 512];
    for (int i = threadIdx.x; i < 3 * C; i += blockDim.x) sw[i] = w[i];
    __syncthreads();
    int total = NB * HW * nch;
    for (int idx = blockIdx.x * blockDim.x + threadIdx.x; idx < total;
         idx += gridDim.x * blockDim.x) {
        int hw = idx % HW;
        int t = idx / HW;
        int ch = t % nch;
        int n = t / nch;
        int c0 = ch * 64;
        const float* fp = feat + ((size_t)n * C + c0) * HW + hw;
        float a0 = 0.f, a1 = 0.f, a2 = 0.f;
        #pragma unroll 8
        for (int c = 0; c < 64; ++c) {
            float v = fp[(size_t)c * HW];
            a0 = fmaf(sw[c0 + c], v, a0);
            a1 = fmaf(sw[C + c0 + c], v, a1);
            a2 = fmaf(sw[2 * C + c0 + c], v, a2);
        }
        float* op = out + (size_t)n * 3 * HW + hw;
        atomicAdd(&op[0], a0);
        atomicAdd(&op[HW], a1);
        atomicAdd(&op[2 * HW], a2);
    }
}

// ---------------- K2: fused (sum of 4 upsampled levels / 4) + guidance concat ----------------
__global__ void k_fused_guid(const float* __restrict__ image,
                             const float* __restrict__ p0, const float* __restrict__ p1,
                             const float* __restrict__ p2, const float* __restrict__ p3,
                             float* __restrict__ guid) {
    const int HW = HF * WF;
    int total = NB * HW;
    int idx = blockIdx.x * blockDim.x + threadIdx.x;
    if (idx >= total) return;
    int n = idx / HW, r = idx - n * HW;
    int y = r / WF, x = r - y * WF;

    const float* ps[4] = {p0, p1, p2, p3};
    const int ss[4] = {256, 128, 64, 32};
    float f[3] = {0.f, 0.f, 0.f};
    #pragma unroll
    for (int l = 0; l < 4; ++l) {
        int s = ss[l];
        float scale = (float)(s - 1) / 511.0f;
        int y0, y1, x0, x1;
        float fy, fx;
        ac_prep(y, scale, s, y0, y1, fy);
        ac_prep(x, scale, s, x0, x1, fx);
        const float* pb = ps[l] + (size_t)n * 3 * s * s;
        #pragma unroll
        for (int o = 0; o < 3; ++o) {
            const float* pp = pb + (size_t)o * s * s;
            float v00 = pp[y0 * s + x0], v01 = pp[y0 * s + x1];
            float v10 = pp[y1 * s + x0], v11 = pp[y1 * s + x1];
            float r0 = v00 * (1.f - fy) + v10 * fy;
            float r1 = v01 * (1.f - fy) + v11 * fy;
            f[o] += r0 * (1.f - fx) + r1 * fx;
        }
    }
    float* gp = guid + (size_t)n * NGU * HW + y * WF + x;
    const float* ip = image + (size_t)n * 3 * HW + y * WF + x;
    #pragma unroll
    for (int o = 0; o < 3; ++o) gp[(size_t)o * HW] = ip[(size_t)o * HW];
    #pragma unroll
    for (int o = 0; o < 3; ++o) gp[(size_t)(3 + o) * HW] = f[o] * 0.25f;
}

// ---------------- K3: generic align-corners bilinear resize ----------------
__global__ void k_resize(const float* __restrict__ in, float* __restrict__ out,
                         int NCtot, int Hi, int Wi, int Ho, int Wo) {
    int total = NCtot * Ho * Wo;
    int idx = blockIdx.x * blockDim.x + threadIdx.x;
    if (idx >= total) return;
    float sy = (float)(Hi - 1) / (float)(Ho - 1);
    float sx = (float)(Wi - 1) / (float)(Wo - 1);
    int nc = idx / (Ho * Wo), r = idx - nc * (Ho * Wo);
    int yo = r / Wo, xo = r - yo * Wo;
    int y0, y1, x0, x1;
    float fy, fx;
    ac_prep(yo, sy, Hi, y0, y1, fy);
    ac_prep(xo, sx, Wi, x0, x1, fx);
    const float* ip = in + (size_t)nc * Hi * Wi;
    float v00 = ip[y0 * Wi + x0], v01 = ip[y0 * Wi + x1];
    float v10 = ip[y1 * Wi + x0], v11 = ip[y1 * Wi + x1];
    float r0 = v00 * (1.f - fy) + v10 * fy;
    float r1 = v01 * (1.f - fy) + v11 * fy;
    out[idx] = r0 * (1.f - fx) + r1 * fx;
}

// ---------------- K_prep1: fold compat into conv weights ----------------
// W2[ci][tap][o] = sum_c cw[o,c]*wbil[c,ci,tap] + (ci<8 ? cw[o,ci]*wsp[ci,tap] : 0)
__global__ void k_prep_w(const float* __restrict__ wsp, const float* __restrict__ wbil,
                         const float* __restrict__ cw, float* __restrict__ W2) {
    int i = blockIdx.x * blockDim.x + threadIdx.x;
    if (i >= NBI * 9 * 8) return;
    int o = i & 7;
    int t = (i >> 3) % 9;
    int ci = i / 72;
    float s = 0.f;
    for (int c = 0; c < NCLS; ++c)
        s += cw[o * NCLS + c] * wbil[((size_t)c * NBI + ci) * 9 + t];
    if (ci < NCLS) s += cw[o * NCLS + ci] * wsp[ci * 9 + t];
    W2[ci * 72 + t * 8 + o] = s;
}

// ---------------- K_prep2: build MFMA B-fragments (fp16) ----------------
// K-order: k = tap*16 + ci (tap 0..8 real, tap 9 pad; ci 0..13 real, 14/15 pad)
// B-frag for MFMA j: lane l holds B[k = j*32 + (l>>4)*8 + e][col = l&15], e=0..7
__global__ void k_prep_frag(const float* __restrict__ W2, _Float16* __restrict__ wf) {
    int i = blockIdx.x * blockDim.x + threadIdx.x;
    if (i >= 5 * 64) return;
    int j = i >> 6, l = i & 63;
    int col = l & 15, kg = l >> 4;
    #pragma unroll
    for (int e = 0; e < 8; ++e) {
        int k = j * 32 + kg * 8 + e;
        int tap = k >> 4, ci = k & 15;
        float v = (tap < 9 && ci < 14 && col < 8) ? W2[ci * 72 + tap * 8 + col] : 0.f;
        wf[i * 8 + e] = (_Float16)v;
    }
}

// ---------------- K5: both mean-field iterations, conv on MFMA ----------------
template <bool ACCUM>
__global__ __launch_bounds__(256, 4) void k_mf_mfma(
    const float* __restrict__ unary, const float* __restrict__ guid,
    float* __restrict__ Qout, const _Float16* __restrict__ wfragG,
    int H, int W) {
    // tile: [px][16ch] fp16, px = yy*36+xx over 20x36 halo; front pad 16, back pad 32
    __shared__ __align__(16) _Float16 s_t[16 + SPX * 16 + 32];
    __shared__ __align__(16) _Float16 s_msg[R1N * 8];   // [px][8ch] fp16
    _Float16* tb = s_t + 16;

    const int tid = threadIdx.x;
    const int lane = tid & 63;
    const int wv = tid >> 6;
    const int n = blockIdx.z;
    const int gx0 = blockIdx.x * TOX;
    const int gy0 = blockIdx.y * TOY;
    const int HW = H * W;
    const float* ubase = unary + (size_t)n * NCLS * HW;
    const float* gbase = guid + (size_t)n * NGU * HW;

    // weight fragments (wave-uniform, L2-broadcast)
    f16x8 wf[5];
    #pragma unroll
    for (int j = 0; j < 5; ++j)
        wf[j] = *(const f16x8*)(wfragG + (j * 64 + lane) * 8);

    // zero guard pads (front 16, back 32 halves)
    if (tid < 16) s_t[tid] = (_Float16)0.f;
    if (tid >= 16 && tid < 48) s_t[16 + SPX * 16 + (tid - 16)] = (_Float16)0.f;

    // ---- stage guidance ch 8..13 (+ zero ch 14,15), as ch-pairs ----
    for (int i = tid; i < 4 * SPX; i += 256) {
        int pr = i / SPX;
        int px = i - pr * SPX;
        int yy = px / SX, xx = px - yy * SX;
        int gy = gy0 + yy - 2, gx = gx0 + xx - 2;
        float a = 0.f, b = 0.f;
        if (pr < 3 && (unsigned)gy < (unsigned)H && (unsigned)gx < (unsigned)W) {
            const float* gp = gbase + (size_t)(2 * pr) * HW + (size_t)gy * W + gx;
            a = gp[0];
            b = gp[HW];
        }
        f16x2 v;
        v.x = (_Float16)a;
        v.y = (_Float16)b;
        *(f16x2*)(tb + px * 16 + 8 + 2 * pr) = v;
    }
    // ---- stage Q0 = softmax(unary) (zero outside image) ----
    for (int i = tid; i < SPX; i += 256) {
        int yy = i / SX, xx = i - yy * SX;
        int gy = gy0 + yy - 2, gx = gx0 + xx - 2;
        f16x8 q;
        #pragma unroll
        for (int o = 0; o < 8; ++o) q[o] = (_Float16)0.f;
        if ((unsigned)gy < (unsigned)H && (unsigned)gx < (unsigned)W) {
            const float* up = ubase + (size_t)gy * W + gx;
            float e[8];
            float s = 0.f;
            #pragma unroll
            for (int o = 0; o < 8; ++o) { e[o] = __expf(up[(size_t)o * HW]); s += e[o]; }
            float inv = 1.f / s;
            #pragma unroll
            for (int o = 0; o < 8; ++o) q[o] = (_Float16)(e[o] * inv);
        }
        *(f16x8*)(tb + i * 16) = q;
    }
    __syncthreads();

    // ================= iteration 1: rows 1..18 x cols 0..35 =================
    for (int t = wv; t < R1T; t += 4) {
        int pb = t * 16;
        int p = pb + (lane & 15);
        if (p > R1N - 1) p = R1N - 1;
        int qy = p / R1W;
        int yy = 1 + qy, xx = p - qy * R1W;
        int kg = lane >> 4;
        f32x4 acc = {0.f, 0.f, 0.f, 0.f};
        #pragma unroll
        for (int j = 0; j < 5; ++j) {
            int tap = 2 * j + (kg >> 1);
            if (tap > 8) tap = 8;  // pad-K: B is zero there, read anything valid
            int dy = tap / 3 - 1, dx = tap - (tap / 3) * 3 - 1;
            int idx = (yy + dy) * SX + (xx + dx);
            f16x8 af = *(const f16x8*)(tb + idx * 16 + (kg & 1) * 8);
            acc = __builtin_amdgcn_mfma_f32_16x16x32_f16(af, wf[j], acc, 0, 0, 0);
        }
        int ch = lane & 15;
        if (ch < 8) {
            int pxb = pb + (lane >> 4) * 4;
            #pragma unroll
            for (int r = 0; r < 4; ++r) {
                int px = pxb + r;
                if (px < R1N) s_msg[px * 8 + ch] = (_Float16)acc[r];
            }
        }
    }
    __syncthreads();
    // epilogue 1: Q1 = softmax(unary - msg) -> back into tile (idx = i + 36)
    for (int i = tid; i < R1N; i += 256) {
        int qy = i / R1W;
        int yy = 1 + qy, xx = i - qy * R1W;
        int gy = gy0 + yy - 2, gx = gx0 + xx - 2;
        f16x8 q;
        #pragma unroll
        for (int o = 0; o < 8; ++o) q[o] = (_Float16)0.f;
        if ((unsigned)gy < (unsigned)H && (unsigned)gx < (unsigned)W) {
            f16x8 m = *(const f16x8*)(s_msg + i * 8);
            const float* up = ubase + (size_t)gy * W + gx;
            float e[8];
            float s = 0.f;
            #pragma unroll
            for (int o = 0; o < 8; ++o) {
                e[o] = __expf(up[(size_t)o * HW] - (float)m[o]);
                s += e[o];
            }
            float inv = 1.f / s;
            #pragma unroll
            for (int o = 0; o < 8; ++o) q[o] = (_Float16)(e[o] * inv);
        }
        *(f16x8*)(tb + (i + SX) * 16) = q;
    }
    __syncthreads();

    // ================= iteration 2: rows 2..17 x cols 2..33 =================
    for (int t = wv; t < R2T; t += 4) {
        int pb = t * 16;
        int p = pb + (lane & 15);
        int yy = 2 + (p >> 5), xx = 2 + (p & 31);
        int kg = lane >> 4;
        f32x4 acc = {0.f, 0.f, 0.f, 0.f};
        #pragma unroll
        for (int j = 0; j < 5; ++j) {
            int tap = 2 * j + (kg >> 1);
            if (tap > 8) tap = 8;
            int dy = tap / 3 - 1, dx = tap - (tap / 3) * 3 - 1;
            int idx = (yy + dy) * SX + (xx + dx);
            f16x8 af = *(const f16x8*)(tb + idx * 16 + (kg & 1) * 8);
            acc = __builtin_amdgcn_mfma_f32_16x16x32_f16(af, wf[j], acc, 0, 0, 0);
        }
        int ch = lane & 15;
        if (ch < 8) {
            int pxb = pb + (lane >> 4) * 4;
            #pragma unroll
            for (int r = 0; r < 4; ++r) s_msg[(pxb + r) * 8 + ch] = (_Float16)acc[r];
        }
    }
    __syncthreads();
    // epilogue 2: write/accumulate to global (all px in-image)
    for (int i = tid; i < R2N; i += 256) {
        int gy = gy0 + (i >> 5), gx = gx0 + (i & 31);
        f16x8 m = *(const f16x8*)(s_msg + i * 8);
        const float* up = ubase + (size_t)gy * W + gx;
        float e[8];
        float s = 0.f;
        #pragma unroll
        for (int o = 0; o < 8; ++o) {
            e[o] = __expf(up[(size_t)o * HW] - (float)m[o]);
            s += e[o];
        }
        float inv = (ACCUM ? 0.5f : 1.f) / s;
        float* qp = Qout + (size_t)n * NCLS * HW + (size_t)gy * W + gx;
        #pragma unroll
        for (int o = 0; o < 8; ++o) {
            if (ACCUM)
                qp[(size_t)o * HW] += e[o] * inv;
            else
                qp[(size_t)o * HW] = e[o] * inv;
        }
    }
}

// ---------------- K6: out = 0.5 * upsample(Q_down) ----------------
__global__ void k_upcombine(const float* __restrict__ Qd, float* __restrict__ out) {
    const int HW = HF * WF;
    int total = NB * NCLS * HW;
    int idx = blockIdx.x * blockDim.x + threadIdx.x;
    if (idx >= total) return;
    int nc = idx / HW, r = idx - nc * HW;
    int y = r / WF, x = r - y * WF;
    const float sc = 255.f / 511.f;
    int y0, y1, x0, x1;
    float fy, fx;
    ac_prep(y, sc, HH, y0, y1, fy);
    ac_prep(x, sc, WH, x0, x1, fx);
    const float* qp = Qd + (size_t)nc * (HH * WH);
    float v00 = qp[y0 * WH + x0], v01 = qp[y0 * WH + x1];
    float v10 = qp[y1 * WH + x0], v11 = qp[y1 * WH + x1];
    float r0 = v00 * (1.f - fy) + v10 * fy;
    float r1 = v01 * (1.f - fy) + v11 * fy;
    out[idx] = 0.5f * (r0 * (1.f - fx) + r1 * fx);
}

static inline int cdiv(int a, int b) { return (a + b - 1) / b; }

extern "C" void kernel_launch(void* const* d_in, const int* in_sizes, int n_in,
                              void* d_out, int out_size, void* d_ws, size_t ws_size,
                              hipStream_t stream) {
    const float* logits = (const float*)d_in[0];
    const float* image = (const float*)d_in[1];
    const float* skip0 = (const float*)d_in[2];
    const float* skip1 = (const float*)d_in[3];
    const float* skip2 = (const float*)d_in[4];
    const float* skip3 = (const float*)d_in[5];
    const float* spatial_w = (const float*)d_in[6];
    const float* bilateral_w = (const float*)d_in[7];
    const float* compat_w = (const float*)d_in[8];
    const float* skip_w0 = (const float*)d_in[9];
    const float* skip_b0 = (const float*)d_in[10];
    const float* skip_w1 = (const float*)d_in[11];
    const float* skip_b1 = (const float*)d_in[12];
    const float* skip_w2 = (const float*)d_in[13];
    const float* skip_b2 = (const float*)d_in[14];
    const float* skip_w3 = (const float*)d_in[15];
    const float* skip_b3 = (const float*)d_in[16];
    float* out = (float*)d_out;
    float* ws = (float*)d_ws;

    // workspace layout (floats). Region A time-shared:
    //  phase 1: p0..p3 ; phase 2: logits_d/guid_d/Qa_d
    float* p0 = ws + 0;
    float* p1 = p0 + (size_t)NB * 3 * 256 * 256;
    float* p2 = p1 + (size_t)NB * 3 * 128 * 128;
    float* p3 = p2 + (size_t)NB * 3 * 64 * 64;
    float* logits_d = ws + 0;
    float* guid_d = ws + 4194304;
    float* Qa_d = ws + 7340032;
    float* W2 = ws + 16000000;
    _Float16* wfrag = (_Float16*)(ws + 16100000);
    float* guid = ws + 16777216;

    const int HWf = HF * WF;
    const int HWh = HH * WH;

    // --- weight prep: fold compat, then build MFMA fragments ---
    k_prep_w<<<4, 256, 0, stream>>>(spatial_w, bilateral_w, compat_w, W2);
    k_prep_frag<<<2, 256, 0, stream>>>(W2, wfrag);

    // --- skip projections ---
    k_fill_bias<<<cdiv(NB * 3 * 65536, 256), 256, 0, stream>>>(p0, skip_b0, 65536);
    k_fill_bias<<<cdiv(NB * 3 * 16384, 256), 256, 0, stream>>>(p1, skip_b1, 16384);
    k_fill_bias<<<cdiv(NB * 3 * 4096, 256), 256, 0, stream>>>(p2, skip_b2, 4096);
    k_fill_bias<<<cdiv(NB * 3 * 1024, 256), 256, 0, stream>>>(p3, skip_b3, 1024);

    k_skip_proj<<<cdiv(NB * 65536 * 1, 256), 256, 0, stream>>>(skip0, skip_w0, p0, 64, 65536, 1);
    k_skip_proj<<<cdiv(NB * 16384 * 2, 256), 256, 0, stream>>>(skip1, skip_w1, p1, 128, 16384, 2);
    k_skip_proj<<<cdiv(NB * 4096 * 4, 256), 256, 0, stream>>>(skip2, skip_w2, p2, 256, 4096, 4);
    k_skip_proj<<<cdiv(NB * 1024 * 8, 256), 256, 0, stream>>>(skip3, skip_w3, p3, 512, 1024, 8);

    // --- fused + guidance ---
    k_fused_guid<<<cdiv(NB * HWf, 256), 256, 0, stream>>>(image, p0, p1, p2, p3, guid);

    // --- downsample logits & guidance ---
    k_resize<<<cdiv(NB * NCLS * HWh, 256), 256, 0, stream>>>(logits, logits_d, NB * NCLS, HF, WF, HH, WH);
    k_resize<<<cdiv(NB * NGU * HWh, 256), 256, 0, stream>>>(guid, guid_d, NB * NGU, HF, WF, HH, WH);

    // --- half-res mean field (fused, MFMA) ---
    {
        dim3 grid(WH / TOX, HH / TOY, NB);
        k_mf_mfma<false><<<grid, 256, 0, stream>>>(logits_d, guid_d, Qa_d, wfrag, HH, WH);
    }

    // --- out = 0.5 * up(Q_down) ---
    k_upcombine<<<cdiv(NB * NCLS * HWf, 256), 256, 0, stream>>>(Qa_d, out);

    // --- full-res mean field (fused, MFMA), accumulating 0.5*Q into out ---
    {
        dim3 grid(WF / TOX, HF / TOY, NB);
        k_mf_mfma<true><<<grid, 256, 0, stream>>>(logits, guid, out, wfrag, HF, WF);
    }
}

// Round 5
// 235.321 us; speedup vs baseline: 3.1018x; 1.2912x over previous
//
#include <hip/hip_runtime.h>
#include <hip/hip_fp16.h>
#include <math.h>

#define NB 8
#define NCLS 8
#define NGU 6
#define NBI 14
#define HF 512
#define WF 512
#define HH 256
#define WH 256

// MFMA mean-field tile: 32x16 output, 36x20 staged halo
#define TOX 32
#define TOY 16
#define SX 36
#define SY 20
#define SPX (SY * SX)     // 720 staged px
#define R1W 36
#define R1N (18 * 36)     // iter1 region: rows 1..18 x cols 0..35 = 648 px
#define R1T 41            // ceil(648/16)
#define R2N (TOX * TOY)   // 512
#define R2T 32

typedef _Float16 f16x8 __attribute__((ext_vector_type(8)));
typedef float f32x4 __attribute__((ext_vector_type(4)));

static __device__ __forceinline__ void ac_prep(int o, float scale, int insz,
                                               int& i0, int& i1, float& f) {
    float s = (float)o * scale;
    int ii = (int)floorf(s);
    if (ii > insz - 1) ii = insz - 1;
    if (ii < 0) ii = 0;
    i0 = ii;
    i1 = (ii + 1 < insz) ? (ii + 1) : (insz - 1);
    f = s - (float)ii;
}

// ---------------- K0: fill p buffers with bias ----------------
__global__ void k_fill_bias(float* __restrict__ out, const float* __restrict__ b, int HW) {
    int total = NB * 3 * HW;
    int idx = blockIdx.x * blockDim.x + threadIdx.x;
    if (idx >= total) return;
    int o = (idx / HW) % 3;
    out[idx] = b[o];
}

// ---------------- K1: skip 1x1 projection ----------------
// DIRECT: single channel-chunk covers all of C -> write bias+sum directly.
template <bool DIRECT>
__global__ void k_skip_proj(const float* __restrict__ feat, const float* __restrict__ w,
                            const float* __restrict__ b, float* __restrict__ out,
                            int C, int HW, int nch) {
    __shared__ float sw[3 * 512];
    for (int i = threadIdx.x; i < 3 * C; i += blockDim.x) sw[i] = w[i];
    __syncthreads();
    int total = NB * HW * nch;
    for (int idx = blockIdx.x * blockDim.x + threadIdx.x; idx < total;
         idx += gridDim.x * blockDim.x) {
        int hw = idx % HW;
        int t = idx / HW;
        int ch = t % nch;
        int n = t / nch;
        int c0 = ch * 64;
        const float* fp = feat + ((size_t)n * C + c0) * HW + hw;
        float a0 = 0.f, a1 = 0.f, a2 = 0.f;
        #pragma unroll 8
        for (int c = 0; c < 64; ++c) {
            float v = fp[(size_t)c * HW];
            a0 = fmaf(sw[c0 + c], v, a0);
            a1 = fmaf(sw[C + c0 + c], v, a1);
            a2 = fmaf(sw[2 * C + c0 + c], v, a2);
        }
        float* op = out + (size_t)n * 3 * HW + hw;
        if (DIRECT) {
            op[0] = b[0] + a0;
            op[HW] = b[1] + a1;
            op[2 * HW] = b[2] + a2;
        } else {
            atomicAdd(&op[0], a0);
            atomicAdd(&op[HW], a1);
            atomicAdd(&op[2 * HW], a2);
        }
    }
}

// ---------------- K2: fused (sum of 4 upsampled levels / 4) + guidance concat ----------------
__global__ void k_fused_guid(const float* __restrict__ image,
                             const float* __restrict__ p0, const float* __restrict__ p1,
                             const float* __restrict__ p2, const float* __restrict__ p3,
                             float* __restrict__ guid) {
    const int HW = HF * WF;
    int total = NB * HW;
    int idx = blockIdx.x * blockDim.x + threadIdx.x;
    if (idx >= total) return;
    int n = idx / HW, r = idx - n * HW;
    int y = r / WF, x = r - y * WF;

    const float* ps[4] = {p0, p1, p2, p3};
    const int ss[4] = {256, 128, 64, 32};
    float f[3] = {0.f, 0.f, 0.f};
    #pragma unroll
    for (int l = 0; l < 4; ++l) {
        int s = ss[l];
        float scale = (float)(s - 1) / 511.0f;
        int y0, y1, x0, x1;
        float fy, fx;
        ac_prep(y, scale, s, y0, y1, fy);
        ac_prep(x, scale, s, x0, x1, fx);
        const float* pb = ps[l] + (size_t)n * 3 * s * s;
        #pragma unroll
        for (int o = 0; o < 3; ++o) {
            const float* pp = pb + (size_t)o * s * s;
            float v00 = pp[y0 * s + x0], v01 = pp[y0 * s + x1];
            float v10 = pp[y1 * s + x0], v11 = pp[y1 * s + x1];
            float r0 = v00 * (1.f - fy) + v10 * fy;
            float r1 = v01 * (1.f - fy) + v11 * fy;
            f[o] += r0 * (1.f - fx) + r1 * fx;
        }
    }
    float* gp = guid + (size_t)n * NGU * HW + y * WF + x;
    const float* ip = image + (size_t)n * 3 * HW + y * WF + x;
    #pragma unroll
    for (int o = 0; o < 3; ++o) gp[(size_t)o * HW] = ip[(size_t)o * HW];
    #pragma unroll
    for (int o = 0; o < 3; ++o) gp[(size_t)(3 + o) * HW] = f[o] * 0.25f;
}

// ---------------- K_prep1: fold compat into conv weights ----------------
__global__ void k_prep_w(const float* __restrict__ wsp, const float* __restrict__ wbil,
                         const float* __restrict__ cw, float* __restrict__ W2) {
    int i = blockIdx.x * blockDim.x + threadIdx.x;
    if (i >= NBI * 9 * 8) return;
    int o = i & 7;
    int t = (i >> 3) % 9;
    int ci = i / 72;
    float s = 0.f;
    for (int c = 0; c < NCLS; ++c)
        s += cw[o * NCLS + c] * wbil[((size_t)c * NBI + ci) * 9 + t];
    if (ci < NCLS) s += cw[o * NCLS + ci] * wsp[ci * 9 + t];
    W2[ci * 72 + t * 8 + o] = s;
}

// ---------------- K_prep2: build MFMA B-fragments (fp16) ----------------
__global__ void k_prep_frag(const float* __restrict__ W2, _Float16* __restrict__ wf) {
    int i = blockIdx.x * blockDim.x + threadIdx.x;
    if (i >= 5 * 64) return;
    int j = i >> 6, l = i & 63;
    int col = l & 15, kg = l >> 4;
    #pragma unroll
    for (int e = 0; e < 8; ++e) {
        int k = j * 32 + kg * 8 + e;
        int tap = k >> 4, ci = k & 15;
        float v = (tap < 9 && ci < 14 && col < 8) ? W2[ci * 72 + tap * 8 + col] : 0.f;
        wf[i * 8 + e] = (_Float16)v;
    }
}

// ---------------- K5: both mean-field iterations, conv on MFMA ----------------
// DOWN:   unary/guid are FULL-res (Hs,Ws); staging does align-corners bilinear gather.
// UPFOLD: epilogue2 writes out = 0.5*Q2 + 0.5*bilerp(Qd).
// Epilogues use softmax shift-invariance: Q1 = norm(Q0*exp(-m1)), Q2 = norm(Q1*exp(m1-m2))
// -> unary is read exactly once (staging).
template <bool DOWN, bool UPFOLD>
__global__ __launch_bounds__(256, 4) void k_mf_mfma(
    const float* __restrict__ unary, const float* __restrict__ guid,
    const float* __restrict__ Qd, float* __restrict__ Qout,
    const _Float16* __restrict__ wfragG, int H, int W, int Hs, int Ws) {
    __shared__ __align__(16) _Float16 s_t[16 + SPX * 16 + 32];
    __shared__ __align__(16) _Float16 s_msg[R1N * 8];
    _Float16* tb = s_t + 16;

    const int tid = threadIdx.x;
    const int lane = tid & 63;
    const int wv = tid >> 6;
    const int n = blockIdx.z;
    const int gx0 = blockIdx.x * TOX;
    const int gy0 = blockIdx.y * TOY;
    const int HW = H * W;
    const int HWs = Hs * Ws;
    const float* ubase = unary + (size_t)n * NCLS * HWs;
    const float* gbase = guid + (size_t)n * NGU * HWs;

    // weight fragments (wave-uniform, L2-broadcast)
    f16x8 wf[5];
    #pragma unroll
    for (int j = 0; j < 5; ++j)
        wf[j] = *(const f16x8*)(wfragG + (j * 64 + lane) * 8);

    // zero guard pads
    if (tid < 16) s_t[tid] = (_Float16)0.f;
    if (tid >= 16 && tid < 48) s_t[16 + SPX * 16 + (tid - 16)] = (_Float16)0.f;

    // ---- stage: Q0 = softmax(unary), guidance; zero outside image ----
    const float syc = DOWN ? (float)(Hs - 1) / (float)(H - 1) : 1.f;
    const float sxc = DOWN ? (float)(Ws - 1) / (float)(W - 1) : 1.f;
    for (int i = tid; i < SPX; i += 256) {
        int yy = i / SX, xx = i - yy * SX;
        int gy = gy0 + yy - 2, gx = gx0 + xx - 2;
        f16x8 qv, gv;
        #pragma unroll
        for (int o = 0; o < 8; ++o) { qv[o] = (_Float16)0.f; gv[o] = (_Float16)0.f; }
        if ((unsigned)gy < (unsigned)H && (unsigned)gx < (unsigned)W) {
            float u[8], g[6];
            if (DOWN) {
                int y0, y1, x0, x1;
                float fy, fx;
                ac_prep(gy, syc, Hs, y0, y1, fy);
                ac_prep(gx, sxc, Ws, x0, x1, fx);
                const float w00 = (1.f - fy) * (1.f - fx), w01 = (1.f - fy) * fx;
                const float w10 = fy * (1.f - fx), w11 = fy * fx;
                const size_t o00 = (size_t)y0 * Ws + x0, o01 = (size_t)y0 * Ws + x1;
                const size_t o10 = (size_t)y1 * Ws + x0, o11 = (size_t)y1 * Ws + x1;
                #pragma unroll
                for (int o = 0; o < 8; ++o) {
                    const float* up = ubase + (size_t)o * HWs;
                    u[o] = w00 * up[o00] + w01 * up[o01] + w10 * up[o10] + w11 * up[o11];
                }
                #pragma unroll
                for (int c = 0; c < 6; ++c) {
                    const float* gp = gbase + (size_t)c * HWs;
                    g[c] = w00 * gp[o00] + w01 * gp[o01] + w10 * gp[o10] + w11 * gp[o11];
                }
            } else {
                const size_t off = (size_t)gy * W + gx;
                #pragma unroll
                for (int o = 0; o < 8; ++o) u[o] = ubase[(size_t)o * HWs + off];
                #pragma unroll
                for (int c = 0; c < 6; ++c) g[c] = gbase[(size_t)c * HWs + off];
            }
            float e[8];
            float s = 0.f;
            #pragma unroll
            for (int o = 0; o < 8; ++o) { e[o] = __expf(u[o]); s += e[o]; }
            float inv = 1.f / s;
            #pragma unroll
            for (int o = 0; o < 8; ++o) qv[o] = (_Float16)(e[o] * inv);
            #pragma unroll
            for (int c = 0; c < 6; ++c) gv[c] = (_Float16)g[c];
        }
        *(f16x8*)(tb + i * 16) = qv;
        *(f16x8*)(tb + i * 16 + 8) = gv;
    }
    __syncthreads();

    // ================= iteration 1 MFMA: rows 1..18 x cols 0..35 =================
    for (int t = wv; t < R1T; t += 4) {
        int pb = t * 16;
        int p = pb + (lane & 15);
        if (p > R1N - 1) p = R1N - 1;
        int qy = p / R1W;
        int yy = 1 + qy, xx = p - qy * R1W;
        int kg = lane >> 4;
        f32x4 acc = {0.f, 0.f, 0.f, 0.f};
        #pragma unroll
        for (int j = 0; j < 5; ++j) {
            int tap = 2 * j + (kg >> 1);
            if (tap > 8) tap = 8;
            int dy = tap / 3 - 1, dx = tap - (tap / 3) * 3 - 1;
            int idx = (yy + dy) * SX + (xx + dx);
            f16x8 af = *(const f16x8*)(tb + idx * 16 + (kg & 1) * 8);
            acc = __builtin_amdgcn_mfma_f32_16x16x32_f16(af, wf[j], acc, 0, 0, 0);
        }
        int ch = lane & 15;
        if (ch < 8) {
            int pxb = pb + (lane >> 4) * 4;
            #pragma unroll
            for (int r = 0; r < 4; ++r) {
                int px = pxb + r;
                if (px < R1N) s_msg[px * 8 + ch] = (_Float16)acc[r];
            }
        }
    }
    __syncthreads();

    // ---- epilogue 1: Q1 = norm(Q0 * exp(-m1)) in-place in tile ----
    for (int i = tid; i < R1N; i += 256) {
        int qy = i / R1W;
        int yy = 1 + qy, xx = i - qy * R1W;
        int gy = gy0 + yy - 2, gx = gx0 + xx - 2;
        if ((unsigned)gy < (unsigned)H && (unsigned)gx < (unsigned)W) {
            f16x8 m = *(const f16x8*)(s_msg + i * 8);
            f16x8 q0 = *(const f16x8*)(tb + (i + SX) * 16);
            float e[8];
            float s = 0.f;
            #pragma unroll
            for (int o = 0; o < 8; ++o) {
                e[o] = (float)q0[o] * __expf(-(float)m[o]);
                s += e[o];
            }
            float inv = 1.f / s;
            f16x8 q1;
            #pragma unroll
            for (int o = 0; o < 8; ++o) q1[o] = (_Float16)(e[o] * inv);
            *(f16x8*)(tb + (i + SX) * 16) = q1;
        }
    }
    // capture m1 for this thread's two output px (s_msg still holds m1)
    f16x8 m1r[2];
    #pragma unroll
    for (int u2 = 0; u2 < 2; ++u2) {
        int i = tid + 256 * u2;
        int oy = i >> 5, ox = i & 31;
        int r1 = (1 + oy) * R1W + (2 + ox);
        m1r[u2] = *(const f16x8*)(s_msg + r1 * 8);
    }
    __syncthreads();

    // ================= iteration 2 MFMA: rows 2..17 x cols 2..33 =================
    for (int t = wv; t < R2T; t += 4) {
        int pb = t * 16;
        int p = pb + (lane & 15);
        int yy = 2 + (p >> 5), xx = 2 + (p & 31);
        int kg = lane >> 4;
        f32x4 acc = {0.f, 0.f, 0.f, 0.f};
        #pragma unroll
        for (int j = 0; j < 5; ++j) {
            int tap = 2 * j + (kg >> 1);
            if (tap > 8) tap = 8;
            int dy = tap / 3 - 1, dx = tap - (tap / 3) * 3 - 1;
            int idx = (yy + dy) * SX + (xx + dx);
            f16x8 af = *(const f16x8*)(tb + idx * 16 + (kg & 1) * 8);
            acc = __builtin_amdgcn_mfma_f32_16x16x32_f16(af, wf[j], acc, 0, 0, 0);
        }
        int ch = lane & 15;
        if (ch < 8) {
            int pxb = pb + (lane >> 4) * 4;
            #pragma unroll
            for (int r = 0; r < 4; ++r) s_msg[(pxb + r) * 8 + ch] = (_Float16)acc[r];
        }
    }
    __syncthreads();

    // ---- epilogue 2: Q2 = norm(Q1 * exp(m1 - m2)); write (+fold upsample) ----
    #pragma unroll
    for (int u2 = 0; u2 < 2; ++u2) {
        int i = tid + 256 * u2;
        int oy = i >> 5, ox = i & 31;
        int gy = gy0 + oy, gx = gx0 + ox;
        f16x8 m2 = *(const f16x8*)(s_msg + i * 8);
        f16x8 q1 = *(const f16x8*)(tb + ((2 + oy) * SX + (2 + ox)) * 16);
        float e[8];
        float s = 0.f;
        #pragma unroll
        for (int o = 0; o < 8; ++o) {
            e[o] = (float)q1[o] * __expf((float)m1r[u2][o] - (float)m2[o]);
            s += e[o];
        }
        float inv = 1.f / s;
        float* qp = Qout + (size_t)n * NCLS * HW + (size_t)gy * W + gx;
        if (UPFOLD) {
            int y0, y1, x0, x1;
            float fy, fx;
            ac_prep(gy, 255.f / 511.f, HH, y0, y1, fy);
            ac_prep(gx, 255.f / 511.f, WH, x0, x1, fx);
            const float w00 = (1.f - fy) * (1.f - fx), w01 = (1.f - fy) * fx;
            const float w10 = fy * (1.f - fx), w11 = fy * fx;
            const size_t o00 = (size_t)y0 * WH + x0, o01 = (size_t)y0 * WH + x1;
            const size_t o10 = (size_t)y1 * WH + x0, o11 = (size_t)y1 * WH + x1;
            const float* qd = Qd + (size_t)n * NCLS * (HH * WH);
            #pragma unroll
            for (int o = 0; o < 8; ++o) {
                const float* qq = qd + (size_t)o * (HH * WH);
                float v = w00 * qq[o00] + w01 * qq[o01] + w10 * qq[o10] + w11 * qq[o11];
                qp[(size_t)o * HW] = fmaf(0.5f, e[o] * inv, 0.5f * v);
            }
        } else {
            #pragma unroll
            for (int o = 0; o < 8; ++o) qp[(size_t)o * HW] = e[o] * inv;
        }
    }
}

static inline int cdiv(int a, int b) { return (a + b - 1) / b; }

extern "C" void kernel_launch(void* const* d_in, const int* in_sizes, int n_in,
                              void* d_out, int out_size, void* d_ws, size_t ws_size,
                              hipStream_t stream) {
    const float* logits = (const float*)d_in[0];
    const float* image = (const float*)d_in[1];
    const float* skip0 = (const float*)d_in[2];
    const float* skip1 = (const float*)d_in[3];
    const float* skip2 = (const float*)d_in[4];
    const float* skip3 = (const float*)d_in[5];
    const float* spatial_w = (const float*)d_in[6];
    const float* bilateral_w = (const float*)d_in[7];
    const float* compat_w = (const float*)d_in[8];
    const float* skip_w0 = (const float*)d_in[9];
    const float* skip_b0 = (const float*)d_in[10];
    const float* skip_w1 = (const float*)d_in[11];
    const float* skip_b1 = (const float*)d_in[12];
    const float* skip_w2 = (const float*)d_in[13];
    const float* skip_b2 = (const float*)d_in[14];
    const float* skip_w3 = (const float*)d_in[15];
    const float* skip_b3 = (const float*)d_in[16];
    float* out = (float*)d_out;
    float* ws = (float*)d_ws;

    // workspace layout (floats):
    //  [0 .. 2088960)        : p0..p3 (dead after k_fused_guid)
    //  [4194304 .. 6291456)  : Qa_d (half-res Q, 8*8*256*256)
    //  [16000000 ..]         : W2 (1008)
    //  [16100000 ..]         : wfrag (2560 halves)
    //  [16777216 ..29360128) : guid (8*6*512*512)
    float* p0 = ws + 0;
    float* p1 = p0 + (size_t)NB * 3 * 256 * 256;
    float* p2 = p1 + (size_t)NB * 3 * 128 * 128;
    float* p3 = p2 + (size_t)NB * 3 * 64 * 64;
    float* Qa_d = ws + 4194304;
    float* W2 = ws + 16000000;
    _Float16* wfrag = (_Float16*)(ws + 16100000);
    float* guid = ws + 16777216;

    const int HWf = HF * WF;

    // --- weight prep ---
    k_prep_w<<<4, 256, 0, stream>>>(spatial_w, bilateral_w, compat_w, W2);
    k_prep_frag<<<2, 256, 0, stream>>>(W2, wfrag);

    // --- skip projections ---
    k_fill_bias<<<cdiv(NB * 3 * 16384, 256), 256, 0, stream>>>(p1, skip_b1, 16384);
    k_fill_bias<<<cdiv(NB * 3 * 4096, 256), 256, 0, stream>>>(p2, skip_b2, 4096);
    k_fill_bias<<<cdiv(NB * 3 * 1024, 256), 256, 0, stream>>>(p3, skip_b3, 1024);

    k_skip_proj<true><<<cdiv(NB * 65536 * 1, 256), 256, 0, stream>>>(skip0, skip_w0, skip_b0, p0, 64, 65536, 1);
    k_skip_proj<false><<<cdiv(NB * 16384 * 2, 256), 256, 0, stream>>>(skip1, skip_w1, skip_b1, p1, 128, 16384, 2);
    k_skip_proj<false><<<cdiv(NB * 4096 * 4, 256), 256, 0, stream>>>(skip2, skip_w2, skip_b2, p2, 256, 4096, 4);
    k_skip_proj<false><<<cdiv(NB * 1024 * 8, 256), 256, 0, stream>>>(skip3, skip_w3, skip_b3, p3, 512, 1024, 8);

    // --- fused + guidance (full res only; half-res gathers on the fly) ---
    k_fused_guid<<<cdiv(NB * HWf, 256), 256, 0, stream>>>(image, p0, p1, p2, p3, guid);

    // --- half-res mean field: bilinear-gather staging from full-res logits/guid ---
    {
        dim3 grid(WH / TOX, HH / TOY, NB);
        k_mf_mfma<true, false><<<grid, 256, 0, stream>>>(logits, guid, nullptr, Qa_d,
                                                         wfrag, HH, WH, HF, WF);
    }

    // --- full-res mean field; epilogue folds in 0.5*upsample(Qa_d) ---
    {
        dim3 grid(WF / TOX, HF / TOY, NB);
        k_mf_mfma<false, true><<<grid, 256, 0, stream>>>(logits, guid, Qa_d, out,
                                                         wfrag, HF, WF, HF, WF);
    }
}

// Round 6
// 230.633 us; speedup vs baseline: 3.1649x; 1.0203x over previous
//
#include <hip/hip_runtime.h>
#include <hip/hip_fp16.h>
#include <math.h>

#define NB 8
#define NCLS 8
#define NGU 6
#define NBI 14
#define HF 512
#define WF 512
#define HH 256
#define WH 256

// MFMA mean-field tile: 32x16 output, 36x20 staged halo
#define TOX 32
#define TOY 16
#define SX 36
#define SY 20
#define SPX (SY * SX)     // 720 staged px
#define R1W 36
#define R1N (18 * 36)     // iter1 region: rows 1..18 x cols 0..35 = 648 px
#define R1T 41            // ceil(648/16)
#define R2T 32
// LDS tile: two planes of [px][8ch] fp16 with zero guards between
#define PLANE (SPX * 8)       // 5760 halves
#define PSTR (PLANE + 32)     // 5792 halves plane stride (guard in between)
#define TILEH (16 + PSTR + PLANE + 16)  // 11584 halves total

typedef _Float16 f16x8 __attribute__((ext_vector_type(8)));
typedef float f32x4 __attribute__((ext_vector_type(4)));

static __device__ __forceinline__ void ac_prep(int o, float scale, int insz,
                                               int& i0, int& i1, float& f) {
    float s = (float)o * scale;
    int ii = (int)floorf(s);
    if (ii > insz - 1) ii = insz - 1;
    if (ii < 0) ii = 0;
    i0 = ii;
    i1 = (ii + 1 < insz) ? (ii + 1) : (insz - 1);
    f = s - (float)ii;
}

// ---------------- K0: fill p buffers with bias ----------------
__global__ void k_fill_bias(float* __restrict__ out, const float* __restrict__ b, int HW) {
    int total = NB * 3 * HW;
    int idx = blockIdx.x * blockDim.x + threadIdx.x;
    if (idx >= total) return;
    int o = (idx / HW) % 3;
    out[idx] = b[o];
}

// ---------------- K1: skip 1x1 projection, VEC px per thread ----------------
template <int VEC, bool DIRECT>
__global__ void k_skip_proj(const float* __restrict__ feat, const float* __restrict__ w,
                            const float* __restrict__ bias, float* __restrict__ out,
                            int C, int HW, int nch) {
    __shared__ float sw[3 * 512];
    for (int i = threadIdx.x; i < 3 * C; i += blockDim.x) sw[i] = w[i];
    __syncthreads();
    const int HWv = HW / VEC;
    int total = NB * HWv * nch;
    for (int idx = blockIdx.x * blockDim.x + threadIdx.x; idx < total;
         idx += gridDim.x * blockDim.x) {
        int hv = idx % HWv;
        int t = idx / HWv;
        int ch = t % nch;
        int n = t / nch;
        int c0 = ch * 64;
        const float* fp = feat + ((size_t)n * C + c0) * HW + (size_t)hv * VEC;
        float a[3][VEC];
        #pragma unroll
        for (int o = 0; o < 3; ++o)
            #pragma unroll
            for (int k = 0; k < VEC; ++k) a[o][k] = 0.f;
        #pragma unroll 4
        for (int c = 0; c < 64; ++c) {
            float v[VEC];
            if constexpr (VEC == 4) {
                float4 t4 = *reinterpret_cast<const float4*>(fp + (size_t)c * HW);
                v[0] = t4.x; v[1] = t4.y; v[2] = t4.z; v[3] = t4.w;
            } else if constexpr (VEC == 2) {
                float2 t2 = *reinterpret_cast<const float2*>(fp + (size_t)c * HW);
                v[0] = t2.x; v[1] = t2.y;
            } else {
                v[0] = fp[(size_t)c * HW];
            }
            #pragma unroll
            for (int o = 0; o < 3; ++o) {
                const float wv = sw[o * C + c0 + c];
                #pragma unroll
                for (int k = 0; k < VEC; ++k) a[o][k] = fmaf(wv, v[k], a[o][k]);
            }
        }
        float* op = out + (size_t)n * 3 * HW + (size_t)hv * VEC;
        #pragma unroll
        for (int o = 0; o < 3; ++o) {
            #pragma unroll
            for (int k = 0; k < VEC; ++k) {
                if (DIRECT)
                    op[(size_t)o * HW + k] = bias[o] + a[o][k];
                else
                    atomicAdd(&op[(size_t)o * HW + k], a[o][k]);
            }
        }
    }
}

// ---------------- K2: build packed fp16 NHWC guidance + Q0 ----------------
// Gh[n][y][x][8] = {img r,g,b, fused0..2, 0, 0};  Q0h[n][y][x][8] = softmax(logits)
__global__ void k_prep_full(const float* __restrict__ logits, const float* __restrict__ image,
                            const float* __restrict__ p0, const float* __restrict__ p1,
                            const float* __restrict__ p2, const float* __restrict__ p3,
                            _Float16* __restrict__ Gh, _Float16* __restrict__ Q0h) {
    const int HW = HF * WF;
    int idx = blockIdx.x * blockDim.x + threadIdx.x;
    if (idx >= NB * HW) return;
    int n = idx / HW, r = idx - n * HW;
    int y = r / WF, x = r - y * WF;

    const float* ps[4] = {p0, p1, p2, p3};
    const int ss[4] = {256, 128, 64, 32};
    float f[3] = {0.f, 0.f, 0.f};
    #pragma unroll
    for (int l = 0; l < 4; ++l) {
        int s = ss[l];
        float scale = (float)(s - 1) / 511.0f;
        int y0, y1, x0, x1;
        float fy, fx;
        ac_prep(y, scale, s, y0, y1, fy);
        ac_prep(x, scale, s, x0, x1, fx);
        const float* pb = ps[l] + (size_t)n * 3 * s * s;
        #pragma unroll
        for (int o = 0; o < 3; ++o) {
            const float* pp = pb + (size_t)o * s * s;
            float v00 = pp[y0 * s + x0], v01 = pp[y0 * s + x1];
            float v10 = pp[y1 * s + x0], v11 = pp[y1 * s + x1];
            float r0 = v00 * (1.f - fy) + v10 * fy;
            float r1 = v01 * (1.f - fy) + v11 * fy;
            f[o] += r0 * (1.f - fx) + r1 * fx;
        }
    }
    const float* ip = image + (size_t)n * 3 * HW + r;
    f16x8 gv;
    #pragma unroll
    for (int o = 0; o < 3; ++o) gv[o] = (_Float16)ip[(size_t)o * HW];
    #pragma unroll
    for (int o = 0; o < 3; ++o) gv[3 + o] = (_Float16)(f[o] * 0.25f);
    gv[6] = (_Float16)0.f;
    gv[7] = (_Float16)0.f;
    *(f16x8*)(Gh + (size_t)idx * 8) = gv;

    const float* up = logits + (size_t)n * NCLS * HW + r;
    float e[8];
    float s = 0.f;
    #pragma unroll
    for (int o = 0; o < 8; ++o) { e[o] = __expf(up[(size_t)o * HW]); s += e[o]; }
    float inv = 1.f / s;
    f16x8 qv;
    #pragma unroll
    for (int o = 0; o < 8; ++o) qv[o] = (_Float16)(e[o] * inv);
    *(f16x8*)(Q0h + (size_t)idx * 8) = qv;
}

// ---------------- K_prep1: fold compat into conv weights ----------------
__global__ void k_prep_w(const float* __restrict__ wsp, const float* __restrict__ wbil,
                         const float* __restrict__ cw, float* __restrict__ W2) {
    int i = blockIdx.x * blockDim.x + threadIdx.x;
    if (i >= NBI * 9 * 8) return;
    int o = i & 7;
    int t = (i >> 3) % 9;
    int ci = i / 72;
    float s = 0.f;
    for (int c = 0; c < NCLS; ++c)
        s += cw[o * NCLS + c] * wbil[((size_t)c * NBI + ci) * 9 + t];
    if (ci < NCLS) s += cw[o * NCLS + ci] * wsp[ci * 9 + t];
    W2[ci * 72 + t * 8 + o] = s;
}

// ---------------- K_prep2: build MFMA B-fragments (fp16) ----------------
__global__ void k_prep_frag(const float* __restrict__ W2, _Float16* __restrict__ wf) {
    int i = blockIdx.x * blockDim.x + threadIdx.x;
    if (i >= 5 * 64) return;
    int j = i >> 6, l = i & 63;
    int col = l & 15, kg = l >> 4;
    #pragma unroll
    for (int e = 0; e < 8; ++e) {
        int k = j * 32 + kg * 8 + e;
        int tap = k >> 4, ci = k & 15;
        float v = (tap < 9 && ci < 14 && col < 8) ? W2[ci * 72 + tap * 8 + col] : 0.f;
        wf[i * 8 + e] = (_Float16)v;
    }
}

// ---------------- K5: both mean-field iterations, conv on MFMA ----------------
// DOWN:   staging bilinear-gathers logits (fp32) + Gh (fp16) from full-res.
// !DOWN:  staging is two 16B loads/px from Q0h/Gh.
// UPFOLD: out(fp32 planar) = 0.5*Q2 + 0.5*bilerp(Qd fp16 NHWC); else write fp16 NHWC.
template <bool DOWN, bool UPFOLD>
__global__ __launch_bounds__(256, 4) void k_mf_mfma(
    const float* __restrict__ unary, const _Float16* __restrict__ Q0h,
    const _Float16* __restrict__ Gh, const _Float16* __restrict__ Qd,
    void* __restrict__ QoutV, const _Float16* __restrict__ wfragG,
    int H, int W, int Hs, int Ws) {
    __shared__ __align__(16) _Float16 s_t[TILEH];
    __shared__ __align__(16) _Float16 s_msg[R1N * 8];
    _Float16* tb0 = s_t + 16;            // Q plane (ci 0..7)
    _Float16* tb1 = s_t + 16 + PSTR;     // guid plane (ci 8..15)

    const int tid = threadIdx.x;
    const int lane = tid & 63;
    const int wv = tid >> 6;
    const int n = blockIdx.z;
    const int gx0 = blockIdx.x * TOX;
    const int gy0 = blockIdx.y * TOY;
    const int HW = H * W;
    const int HWs = Hs * Ws;

    // weight fragments (wave-uniform, L2-broadcast)
    f16x8 wf[5];
    #pragma unroll
    for (int j = 0; j < 5; ++j)
        wf[j] = *(const f16x8*)(wfragG + (j * 64 + lane) * 8);

    // zero guard pads: [0,16), [5776,5808), [11568,11584)
    if (tid < 16) s_t[tid] = (_Float16)0.f;
    else if (tid < 48) s_t[5760 + tid] = (_Float16)0.f;
    else if (tid < 64) s_t[11520 + tid] = (_Float16)0.f;

    // ---- stage: Q0 plane + guid plane ----
    const float syc = DOWN ? (float)(Hs - 1) / (float)(H - 1) : 1.f;
    const float sxc = DOWN ? (float)(Ws - 1) / (float)(W - 1) : 1.f;
    for (int i = tid; i < SPX; i += 256) {
        int yy = i / SX, xx = i - yy * SX;
        int gy = gy0 + yy - 2, gx = gx0 + xx - 2;
        f16x8 qv, gv;
        #pragma unroll
        for (int o = 0; o < 8; ++o) { qv[o] = (_Float16)0.f; gv[o] = (_Float16)0.f; }
        if ((unsigned)gy < (unsigned)H && (unsigned)gx < (unsigned)W) {
            if (DOWN) {
                int y0, y1, x0, x1;
                float fy, fx;
                ac_prep(gy, syc, Hs, y0, y1, fy);
                ac_prep(gx, sxc, Ws, x0, x1, fx);
                const float w00 = (1.f - fy) * (1.f - fx), w01 = (1.f - fy) * fx;
                const float w10 = fy * (1.f - fx), w11 = fy * fx;
                const size_t o00 = (size_t)y0 * Ws + x0, o01 = (size_t)y0 * Ws + x1;
                const size_t o10 = (size_t)y1 * Ws + x0, o11 = (size_t)y1 * Ws + x1;
                // unary: bilinear on fp32 logits, then softmax
                const float* ubase = unary + (size_t)n * NCLS * HWs;
                float e[8];
                float s = 0.f;
                #pragma unroll
                for (int o = 0; o < 8; ++o) {
                    const float* up = ubase + (size_t)o * HWs;
                    float u = w00 * up[o00] + w01 * up[o01] + w10 * up[o10] + w11 * up[o11];
                    e[o] = __expf(u);
                    s += e[o];
                }
                float inv = 1.f / s;
                #pragma unroll
                for (int o = 0; o < 8; ++o) qv[o] = (_Float16)(e[o] * inv);
                // guidance: bilinear on fp16 NHWC
                const size_t gb = (size_t)n * HWs;
                f16x8 ga = *(const f16x8*)(Gh + (gb + o00) * 8);
                f16x8 gb2 = *(const f16x8*)(Gh + (gb + o01) * 8);
                f16x8 gc = *(const f16x8*)(Gh + (gb + o10) * 8);
                f16x8 gd = *(const f16x8*)(Gh + (gb + o11) * 8);
                #pragma unroll
                for (int c = 0; c < 8; ++c) {
                    float g = w00 * (float)ga[c] + w01 * (float)gb2[c] +
                              w10 * (float)gc[c] + w11 * (float)gd[c];
                    gv[c] = (_Float16)g;
                }
            } else {
                const size_t off = ((size_t)n * HW + (size_t)gy * W + gx) * 8;
                qv = *(const f16x8*)(Q0h + off);
                gv = *(const f16x8*)(Gh + off);
            }
        }
        *(f16x8*)(tb0 + i * 8) = qv;
        *(f16x8*)(tb1 + i * 8) = gv;
    }
    __syncthreads();

    // ================= iteration 1 MFMA: rows 1..18 x cols 0..35 =================
    for (int t = wv; t < R1T; t += 4) {
        int pb = t * 16;
        int p = pb + (lane & 15);
        if (p > R1N - 1) p = R1N - 1;
        int qy = p / R1W;
        int yy = 1 + qy, xx = p - qy * R1W;
        int kg = lane >> 4;
        f32x4 acc = {0.f, 0.f, 0.f, 0.f};
        #pragma unroll
        for (int j = 0; j < 5; ++j) {
            int tap = 2 * j + (kg >> 1);
            if (tap > 8) tap = 8;
            int dy = tap / 3 - 1, dx = tap - (tap / 3) * 3 - 1;
            int idx = (yy + dy) * SX + (xx + dx);
            f16x8 af = *(const f16x8*)(tb0 + (kg & 1) * PSTR + idx * 8);
            acc = __builtin_amdgcn_mfma_f32_16x16x32_f16(af, wf[j], acc, 0, 0, 0);
        }
        int ch = lane & 15;
        if (ch < 8) {
            int pxb = pb + (lane >> 4) * 4;
            #pragma unroll
            for (int r = 0; r < 4; ++r) {
                int px = pxb + r;
                if (px < R1N) s_msg[px * 8 + ch] = (_Float16)acc[r];
            }
        }
    }
    __syncthreads();

    // ---- epilogue 1: Q1 = norm(Q0 * exp(-m1)) in-place in Q plane ----
    for (int i = tid; i < R1N; i += 256) {
        int qy = i / R1W;
        int yy = 1 + qy, xx = i - qy * R1W;
        int gy = gy0 + yy - 2, gx = gx0 + xx - 2;
        if ((unsigned)gy < (unsigned)H && (unsigned)gx < (unsigned)W) {
            f16x8 m = *(const f16x8*)(s_msg + i * 8);
            f16x8 q0 = *(const f16x8*)(tb0 + (i + SX) * 8);
            float e[8];
            float s = 0.f;
            #pragma unroll
            for (int o = 0; o < 8; ++o) {
                e[o] = (float)q0[o] * __expf(-(float)m[o]);
                s += e[o];
            }
            float inv = 1.f / s;
            f16x8 q1;
            #pragma unroll
            for (int o = 0; o < 8; ++o) q1[o] = (_Float16)(e[o] * inv);
            *(f16x8*)(tb0 + (i + SX) * 8) = q1;
        }
    }
    // capture m1 for this thread's two output px (s_msg still holds m1)
    f16x8 m1r[2];
    #pragma unroll
    for (int u2 = 0; u2 < 2; ++u2) {
        int i = tid + 256 * u2;
        int oy = i >> 5, ox = i & 31;
        int r1 = (1 + oy) * R1W + (2 + ox);
        m1r[u2] = *(const f16x8*)(s_msg + r1 * 8);
    }
    __syncthreads();

    // ================= iteration 2 MFMA: rows 2..17 x cols 2..33 =================
    for (int t = wv; t < R2T; t += 4) {
        int pb = t * 16;
        int p = pb + (lane & 15);
        int yy = 2 + (p >> 5), xx = 2 + (p & 31);
        int kg = lane >> 4;
        f32x4 acc = {0.f, 0.f, 0.f, 0.f};
        #pragma unroll
        for (int j = 0; j < 5; ++j) {
            int tap = 2 * j + (kg >> 1);
            if (tap > 8) tap = 8;
            int dy = tap / 3 - 1, dx = tap - (tap / 3) * 3 - 1;
            int idx = (yy + dy) * SX + (xx + dx);
            f16x8 af = *(const f16x8*)(tb0 + (kg & 1) * PSTR + idx * 8);
            acc = __builtin_amdgcn_mfma_f32_16x16x32_f16(af, wf[j], acc, 0, 0, 0);
        }
        int ch = lane & 15;
        if (ch < 8) {
            int pxb = pb + (lane >> 4) * 4;
            #pragma unroll
            for (int r = 0; r < 4; ++r) s_msg[(pxb + r) * 8 + ch] = (_Float16)acc[r];
        }
    }
    __syncthreads();

    // ---- epilogue 2: Q2 = norm(Q1 * exp(m1 - m2)); write ----
    #pragma unroll
    for (int u2 = 0; u2 < 2; ++u2) {
        int i = tid + 256 * u2;
        int oy = i >> 5, ox = i & 31;
        int gy = gy0 + oy, gx = gx0 + ox;
        f16x8 m2 = *(const f16x8*)(s_msg + i * 8);
        f16x8 q1 = *(const f16x8*)(tb0 + ((2 + oy) * SX + (2 + ox)) * 8);
        float e[8];
        float s = 0.f;
        #pragma unroll
        for (int o = 0; o < 8; ++o) {
            e[o] = (float)q1[o] * __expf((float)m1r[u2][o] - (float)m2[o]);
            s += e[o];
        }
        float inv = 1.f / s;
        if (UPFOLD) {
            float* qp = (float*)QoutV + (size_t)n * NCLS * HW + (size_t)gy * W + gx;
            int y0, y1, x0, x1;
            float fy, fx;
            ac_prep(gy, 255.f / 511.f, HH, y0, y1, fy);
            ac_prep(gx, 255.f / 511.f, WH, x0, x1, fx);
            const float w00 = (1.f - fy) * (1.f - fx), w01 = (1.f - fy) * fx;
            const float w10 = fy * (1.f - fx), w11 = fy * fx;
            const size_t qb = (size_t)n * (HH * WH);
            f16x8 qa = *(const f16x8*)(Qd + (qb + (size_t)y0 * WH + x0) * 8);
            f16x8 qbv = *(const f16x8*)(Qd + (qb + (size_t)y0 * WH + x1) * 8);
            f16x8 qc = *(const f16x8*)(Qd + (qb + (size_t)y1 * WH + x0) * 8);
            f16x8 qdv = *(const f16x8*)(Qd + (qb + (size_t)y1 * WH + x1) * 8);
            #pragma unroll
            for (int o = 0; o < 8; ++o) {
                float v = w00 * (float)qa[o] + w01 * (float)qbv[o] +
                          w10 * (float)qc[o] + w11 * (float)qdv[o];
                qp[(size_t)o * HW] = fmaf(0.5f, e[o] * inv, 0.5f * v);
            }
        } else {
            _Float16* qo = (_Float16*)QoutV + ((size_t)n * HW + (size_t)gy * W + gx) * 8;
            f16x8 q2;
            #pragma unroll
            for (int o = 0; o < 8; ++o) q2[o] = (_Float16)(e[o] * inv);
            *(f16x8*)qo = q2;
        }
    }
}

static inline int cdiv(int a, int b) { return (a + b - 1) / b; }

extern "C" void kernel_launch(void* const* d_in, const int* in_sizes, int n_in,
                              void* d_out, int out_size, void* d_ws, size_t ws_size,
                              hipStream_t stream) {
    const float* logits = (const float*)d_in[0];
    const float* image = (const float*)d_in[1];
    const float* skip0 = (const float*)d_in[2];
    const float* skip1 = (const float*)d_in[3];
    const float* skip2 = (const float*)d_in[4];
    const float* skip3 = (const float*)d_in[5];
    const float* spatial_w = (const float*)d_in[6];
    const float* bilateral_w = (const float*)d_in[7];
    const float* compat_w = (const float*)d_in[8];
    const float* skip_w0 = (const float*)d_in[9];
    const float* skip_b0 = (const float*)d_in[10];
    const float* skip_w1 = (const float*)d_in[11];
    const float* skip_b1 = (const float*)d_in[12];
    const float* skip_w2 = (const float*)d_in[13];
    const float* skip_b2 = (const float*)d_in[14];
    const float* skip_w3 = (const float*)d_in[15];
    const float* skip_b3 = (const float*)d_in[16];
    float* out = (float*)d_out;
    float* ws = (float*)d_ws;

    // workspace layout (float offsets):
    float* p0 = ws + 0;                    // 8*3*65536 = 1,572,864
    float* p1 = ws + 1572864;              // 393,216
    float* p2 = ws + 1966080;              // 98,304
    float* p3 = ws + 2064384;              // 24,576 -> ends 2,088,960
    float* W2 = ws + 2100000;              // 1008
    _Float16* wfrag = (_Float16*)(ws + 2110000);   // 2560 halves
    _Float16* Q0h = (_Float16*)(ws + 4194304);     // 8*512*512*8 halves = 8,388,608 floats
    _Float16* Gh = (_Float16*)(ws + 12582912);     // 8,388,608 floats
    _Float16* Qdh = (_Float16*)(ws + 20971520);    // 8*256*256*8 halves = 2,097,152 floats

    const int HWf = HF * WF;

    // --- weight prep ---
    k_prep_w<<<4, 256, 0, stream>>>(spatial_w, bilateral_w, compat_w, W2);
    k_prep_frag<<<2, 256, 0, stream>>>(W2, wfrag);

    // --- skip projections (vectorized) ---
    k_fill_bias<<<cdiv(NB * 3 * 16384, 256), 256, 0, stream>>>(p1, skip_b1, 16384);
    k_fill_bias<<<cdiv(NB * 3 * 4096, 256), 256, 0, stream>>>(p2, skip_b2, 4096);
    k_fill_bias<<<cdiv(NB * 3 * 1024, 256), 256, 0, stream>>>(p3, skip_b3, 1024);

    k_skip_proj<4, true><<<cdiv(NB * 16384 * 1, 256), 256, 0, stream>>>(
        skip0, skip_w0, skip_b0, p0, 64, 65536, 1);
    k_skip_proj<4, false><<<cdiv(NB * 4096 * 2, 256), 256, 0, stream>>>(
        skip1, skip_w1, skip_b1, p1, 128, 16384, 2);
    k_skip_proj<2, false><<<cdiv(NB * 2048 * 4, 256), 256, 0, stream>>>(
        skip2, skip_w2, skip_b2, p2, 256, 4096, 4);
    k_skip_proj<1, false><<<cdiv(NB * 1024 * 8, 256), 256, 0, stream>>>(
        skip3, skip_w3, skip_b3, p3, 512, 1024, 8);

    // --- packed guidance + Q0 (fp16 NHWC) ---
    k_prep_full<<<cdiv(NB * HWf, 256), 256, 0, stream>>>(logits, image, p0, p1, p2, p3, Gh, Q0h);

    // --- half-res mean field: gathers from full-res logits + Gh ---
    {
        dim3 grid(WH / TOX, HH / TOY, NB);
        k_mf_mfma<true, false><<<grid, 256, 0, stream>>>(
            logits, nullptr, Gh, nullptr, (void*)Qdh, wfrag, HH, WH, HF, WF);
    }

    // --- full-res mean field; epilogue folds in 0.5*upsample(Qdh) ---
    {
        dim3 grid(WF / TOX, HF / TOY, NB);
        k_mf_mfma<false, true><<<grid, 256, 0, stream>>>(
            nullptr, Q0h, Gh, Qdh, (void*)out, wfrag, HF, WF, HF, WF);
    }
}

// Round 7
// 226.672 us; speedup vs baseline: 3.2202x; 1.0175x over previous
//
#include <hip/hip_runtime.h>
#include <hip/hip_fp16.h>
#include <math.h>

#define NB 8
#define NCLS 8
#define NGU 6
#define NBI 14
#define HF 512
#define WF 512
#define HH 256
#define WH 256

// MFMA mean-field tile: 32x16 output, 36x20 staged halo
#define TOX 32
#define TOY 16
#define SX 36
#define SY 20
#define SPX (SY * SX)     // 720 staged px
#define R1W 36
#define R1N (18 * 36)     // iter1 region: rows 1..18 x cols 0..35 = 648 px
#define R1T 41            // ceil(648/16)
#define R2T 32
// LDS tile: two planes of [px][8ch] fp16 with zero guards between
#define PLANE (SPX * 8)       // 5760 halves
#define PSTR (PLANE + 32)     // 5792 halves plane stride (guard in between)
#define TILEH (16 + PSTR + PLANE + 16)  // 11584 halves total

typedef _Float16 f16x8 __attribute__((ext_vector_type(8)));
typedef float f32x4 __attribute__((ext_vector_type(4)));

static __device__ __forceinline__ void ac_prep(int o, float scale, int insz,
                                               int& i0, int& i1, float& f) {
    float s = (float)o * scale;
    int ii = (int)floorf(s);
    if (ii > insz - 1) ii = insz - 1;
    if (ii < 0) ii = 0;
    i0 = ii;
    i1 = (ii + 1 < insz) ? (ii + 1) : (insz - 1);
    f = s - (float)ii;
}

// async global->LDS, 16B per lane; LDS base must be wave-uniform
static __device__ __forceinline__ void dma16(const _Float16* g, _Float16* l) {
    __builtin_amdgcn_global_load_lds(
        (const __attribute__((address_space(1))) void*)g,
        (__attribute__((address_space(3))) void*)l, 16, 0, 0);
}

// ---------------- K0: fill p1..p3 with bias (one kernel) ----------------
__global__ void k_fill3(float* __restrict__ p1, float* __restrict__ p2,
                        float* __restrict__ p3, const float* __restrict__ b1,
                        const float* __restrict__ b2, const float* __restrict__ b3) {
    int i = blockIdx.x * blockDim.x + threadIdx.x;
    if (i < NB * 3 * 16384) { p1[i] = b1[(i / 16384) % 3]; return; }
    i -= NB * 3 * 16384;
    if (i < NB * 3 * 4096) { p2[i] = b2[(i / 4096) % 3]; return; }
    i -= NB * 3 * 4096;
    if (i < NB * 3 * 1024) p3[i] = b3[(i / 1024) % 3];
}

// ---------------- K1: skip 1x1 projection, VEC px per thread ----------------
template <int VEC, bool DIRECT>
__global__ void k_skip_proj(const float* __restrict__ feat, const float* __restrict__ w,
                            const float* __restrict__ bias, float* __restrict__ out,
                            int C, int HW, int nch) {
    __shared__ float sw[3 * 512];
    for (int i = threadIdx.x; i < 3 * C; i += blockDim.x) sw[i] = w[i];
    __syncthreads();
    const int HWv = HW / VEC;
    int total = NB * HWv * nch;
    for (int idx = blockIdx.x * blockDim.x + threadIdx.x; idx < total;
         idx += gridDim.x * blockDim.x) {
        int hv = idx % HWv;
        int t = idx / HWv;
        int ch = t % nch;
        int n = t / nch;
        int c0 = ch * 64;
        const float* fp = feat + ((size_t)n * C + c0) * HW + (size_t)hv * VEC;
        float a[3][VEC];
        #pragma unroll
        for (int o = 0; o < 3; ++o)
            #pragma unroll
            for (int k = 0; k < VEC; ++k) a[o][k] = 0.f;
        #pragma unroll 4
        for (int c = 0; c < 64; ++c) {
            float v[VEC];
            if constexpr (VEC == 4) {
                float4 t4 = *reinterpret_cast<const float4*>(fp + (size_t)c * HW);
                v[0] = t4.x; v[1] = t4.y; v[2] = t4.z; v[3] = t4.w;
            } else if constexpr (VEC == 2) {
                float2 t2 = *reinterpret_cast<const float2*>(fp + (size_t)c * HW);
                v[0] = t2.x; v[1] = t2.y;
            } else {
                v[0] = fp[(size_t)c * HW];
            }
            #pragma unroll
            for (int o = 0; o < 3; ++o) {
                const float wv = sw[o * C + c0 + c];
                #pragma unroll
                for (int k = 0; k < VEC; ++k) a[o][k] = fmaf(wv, v[k], a[o][k]);
            }
        }
        float* op = out + (size_t)n * 3 * HW + (size_t)hv * VEC;
        #pragma unroll
        for (int o = 0; o < 3; ++o) {
            #pragma unroll
            for (int k = 0; k < VEC; ++k) {
                if (DIRECT)
                    op[(size_t)o * HW + k] = bias[o] + a[o][k];
                else
                    atomicAdd(&op[(size_t)o * HW + k], a[o][k]);
            }
        }
    }
}

// ---------------- K2: build packed fp16 NHWC guidance + Q0 (2 px/thread) ----------------
__global__ void k_prep_full(const float* __restrict__ logits, const float* __restrict__ image,
                            const float* __restrict__ p0, const float* __restrict__ p1,
                            const float* __restrict__ p2, const float* __restrict__ p3,
                            _Float16* __restrict__ Gh, _Float16* __restrict__ Q0h) {
    const int HW = HF * WF;
    int t = blockIdx.x * blockDim.x + threadIdx.x;
    if (t >= NB * HW / 2) return;
    int idx = t * 2;
    int n = idx / HW, r = idx - n * HW;
    int y = r / WF, x = r - y * WF;

    const float* ps[4] = {p0, p1, p2, p3};
    const int ss[4] = {256, 128, 64, 32};
    float f[2][3] = {{0.f, 0.f, 0.f}, {0.f, 0.f, 0.f}};
    #pragma unroll
    for (int l = 0; l < 4; ++l) {
        int s = ss[l];
        float scale = (float)(s - 1) / 511.0f;
        int y0, y1;
        float fy;
        ac_prep(y, scale, s, y0, y1, fy);
        const float* pb = ps[l] + (size_t)n * 3 * s * s;
        #pragma unroll
        for (int k = 0; k < 2; ++k) {
            int x0, x1;
            float fx;
            ac_prep(x + k, scale, s, x0, x1, fx);
            #pragma unroll
            for (int o = 0; o < 3; ++o) {
                const float* pp = pb + (size_t)o * s * s;
                float v00 = pp[y0 * s + x0], v01 = pp[y0 * s + x1];
                float v10 = pp[y1 * s + x0], v11 = pp[y1 * s + x1];
                float r0 = v00 * (1.f - fy) + v10 * fy;
                float r1 = v01 * (1.f - fy) + v11 * fy;
                f[k][o] += r0 * (1.f - fx) + r1 * fx;
            }
        }
    }
    const float* ip = image + (size_t)n * 3 * HW + r;
    float2 img[3];
    #pragma unroll
    for (int o = 0; o < 3; ++o) img[o] = *reinterpret_cast<const float2*>(&ip[(size_t)o * HW]);
    const float* up = logits + (size_t)n * NCLS * HW + r;
    float2 u[8];
    #pragma unroll
    for (int o = 0; o < 8; ++o) u[o] = *reinterpret_cast<const float2*>(&up[(size_t)o * HW]);

    f16x8 gv[2], qv[2];
    #pragma unroll
    for (int k = 0; k < 2; ++k) {
        gv[k][0] = (_Float16)(k ? img[0].y : img[0].x);
        gv[k][1] = (_Float16)(k ? img[1].y : img[1].x);
        gv[k][2] = (_Float16)(k ? img[2].y : img[2].x);
        gv[k][3] = (_Float16)(f[k][0] * 0.25f);
        gv[k][4] = (_Float16)(f[k][1] * 0.25f);
        gv[k][5] = (_Float16)(f[k][2] * 0.25f);
        gv[k][6] = (_Float16)0.f;
        gv[k][7] = (_Float16)0.f;
        float e[8];
        float s = 0.f;
        #pragma unroll
        for (int o = 0; o < 8; ++o) { e[o] = __expf(k ? u[o].y : u[o].x); s += e[o]; }
        float inv = 1.f / s;
        #pragma unroll
        for (int o = 0; o < 8; ++o) qv[k][o] = (_Float16)(e[o] * inv);
    }
    *(f16x8*)(Gh + (size_t)idx * 8) = gv[0];
    *(f16x8*)(Gh + (size_t)idx * 8 + 8) = gv[1];
    *(f16x8*)(Q0h + (size_t)idx * 8) = qv[0];
    *(f16x8*)(Q0h + (size_t)idx * 8 + 8) = qv[1];
}

// ---------------- K_prep: fold compat + build MFMA B-fragments (one kernel) ----------------
__global__ void k_prep_wf(const float* __restrict__ wsp, const float* __restrict__ wbil,
                          const float* __restrict__ cw, _Float16* __restrict__ wf) {
    __shared__ float sW2[NBI * 72];
    int tid = threadIdx.x;
    if (tid < NBI * 72) {
        int o = tid & 7;
        int t = (tid >> 3) % 9;
        int ci = tid / 72;
        float s = 0.f;
        for (int c = 0; c < NCLS; ++c)
            s += cw[o * NCLS + c] * wbil[((size_t)c * NBI + ci) * 9 + t];
        if (ci < NCLS) s += cw[o * NCLS + ci] * wsp[ci * 9 + t];
        sW2[tid] = s;
    }
    __syncthreads();
    if (tid < 5 * 64) {
        int l = tid & 63;
        int col = l & 15, kg = l >> 4;
        #pragma unroll
        for (int e = 0; e < 8; ++e) {
            int k = (tid >> 6) * 32 + kg * 8 + e;
            int tap = k >> 4, ci = k & 15;
            float v = (tap < 9 && ci < 14 && col < 8) ? sW2[ci * 72 + tap * 8 + col] : 0.f;
            wf[tid * 8 + e] = (_Float16)v;
        }
    }
}

// ---------------- K5: both mean-field iterations, conv on MFMA ----------------
// DOWN:   staging bilinear-gathers logits (fp32) + Gh (fp16) from full-res.
// !DOWN:  interior blocks DMA-stage via global_load_lds; boundary blocks masked path.
// UPFOLD: out(fp32 planar) = 0.5*Q2 + 0.5*bilerp(Qd fp16 NHWC); else write fp16 NHWC.
template <bool DOWN, bool UPFOLD>
__global__ __launch_bounds__(256, 4) void k_mf_mfma(
    const float* __restrict__ unary, const _Float16* __restrict__ Q0h,
    const _Float16* __restrict__ Gh, const _Float16* __restrict__ Qd,
    void* __restrict__ QoutV, const _Float16* __restrict__ wfragG,
    int H, int W, int Hs, int Ws) {
    __shared__ __align__(16) _Float16 s_t[TILEH];
    __shared__ __align__(16) _Float16 s_msg[R1N * 8];
    _Float16* tb0 = s_t + 16;            // Q plane (ci 0..7)
    _Float16* tb1 = s_t + 16 + PSTR;     // guid plane (ci 8..15)

    const int tid = threadIdx.x;
    const int lane = tid & 63;
    const int wv = tid >> 6;
    const int n = blockIdx.z;
    const int gx0 = blockIdx.x * TOX;
    const int gy0 = blockIdx.y * TOY;
    const int HW = H * W;
    const int HWs = Hs * Ws;

    // weight fragments (wave-uniform, L2-broadcast)
    f16x8 wf[5];
    #pragma unroll
    for (int j = 0; j < 5; ++j)
        wf[j] = *(const f16x8*)(wfragG + (j * 64 + lane) * 8);

    // zero guard pads: [0,16), [5776,5808), [11568,11584)
    if (tid < 16) s_t[tid] = (_Float16)0.f;
    else if (tid < 48) s_t[5760 + tid] = (_Float16)0.f;
    else if (tid < 64) s_t[11520 + tid] = (_Float16)0.f;

    const bool interior = !DOWN && gx0 >= 2 && (gx0 + TOX + 2) <= W &&
                          gy0 >= 2 && (gy0 + TOY + 2) <= H;

    if (!DOWN && interior) {
        // ---- fast staging: async DMA, 64 px per chunk, 12 chunks per plane ----
        const size_t nb = (size_t)n * HW;
        for (int c = wv; c < 12; c += 4) {
            int px = c * 64 + lane;
            int yy = px / SX, xx = px - yy * SX;
            size_t goff = (nb + (size_t)(gy0 + yy - 2) * W + (gx0 + xx - 2)) * 8;
            if (px < SPX) {
                dma16(Q0h + goff, tb0 + (size_t)c * 64 * 8);
                dma16(Gh + goff, tb1 + (size_t)c * 64 * 8);
            }
        }
    } else {
        const float syc = DOWN ? (float)(Hs - 1) / (float)(H - 1) : 1.f;
        const float sxc = DOWN ? (float)(Ws - 1) / (float)(W - 1) : 1.f;
        for (int i = tid; i < SPX; i += 256) {
            int yy = i / SX, xx = i - yy * SX;
            int gy = gy0 + yy - 2, gx = gx0 + xx - 2;
            f16x8 qv, gv;
            #pragma unroll
            for (int o = 0; o < 8; ++o) { qv[o] = (_Float16)0.f; gv[o] = (_Float16)0.f; }
            if ((unsigned)gy < (unsigned)H && (unsigned)gx < (unsigned)W) {
                if (DOWN) {
                    int y0, y1, x0, x1;
                    float fy, fx;
                    ac_prep(gy, syc, Hs, y0, y1, fy);
                    ac_prep(gx, sxc, Ws, x0, x1, fx);
                    const float w00 = (1.f - fy) * (1.f - fx), w01 = (1.f - fy) * fx;
                    const float w10 = fy * (1.f - fx), w11 = fy * fx;
                    const size_t o00 = (size_t)y0 * Ws + x0, o01 = (size_t)y0 * Ws + x1;
                    const size_t o10 = (size_t)y1 * Ws + x0, o11 = (size_t)y1 * Ws + x1;
                    const float* ubase = unary + (size_t)n * NCLS * HWs;
                    float e[8];
                    float s = 0.f;
                    #pragma unroll
                    for (int o = 0; o < 8; ++o) {
                        const float* up = ubase + (size_t)o * HWs;
                        float u = w00 * up[o00] + w01 * up[o01] + w10 * up[o10] + w11 * up[o11];
                        e[o] = __expf(u);
                        s += e[o];
                    }
                    float inv = 1.f / s;
                    #pragma unroll
                    for (int o = 0; o < 8; ++o) qv[o] = (_Float16)(e[o] * inv);
                    const size_t gb = (size_t)n * HWs;
                    f16x8 ga = *(const f16x8*)(Gh + (gb + o00) * 8);
                    f16x8 gb2 = *(const f16x8*)(Gh + (gb + o01) * 8);
                    f16x8 gc = *(const f16x8*)(Gh + (gb + o10) * 8);
                    f16x8 gd = *(const f16x8*)(Gh + (gb + o11) * 8);
                    #pragma unroll
                    for (int c = 0; c < 8; ++c) {
                        float g = w00 * (float)ga[c] + w01 * (float)gb2[c] +
                                  w10 * (float)gc[c] + w11 * (float)gd[c];
                        gv[c] = (_Float16)g;
                    }
                } else {
                    const size_t off = ((size_t)n * HW + (size_t)gy * W + gx) * 8;
                    qv = *(const f16x8*)(Q0h + off);
                    gv = *(const f16x8*)(Gh + off);
                }
            }
            *(f16x8*)(tb0 + i * 8) = qv;
            *(f16x8*)(tb1 + i * 8) = gv;
        }
    }
    __syncthreads();

    // ================= iteration 1 MFMA: rows 1..18 x cols 0..35 =================
    for (int t = wv; t < R1T; t += 4) {
        int pb = t * 16;
        int p = pb + (lane & 15);
        if (p > R1N - 1) p = R1N - 1;
        int qy = p / R1W;
        int yy = 1 + qy, xx = p - qy * R1W;
        int kg = lane >> 4;
        f32x4 acc = {0.f, 0.f, 0.f, 0.f};
        #pragma unroll
        for (int j = 0; j < 5; ++j) {
            int tap = 2 * j + (kg >> 1);
            if (tap > 8) tap = 8;
            int dy = tap / 3 - 1, dx = tap - (tap / 3) * 3 - 1;
            int idx = (yy + dy) * SX + (xx + dx);
            f16x8 af = *(const f16x8*)(tb0 + (kg & 1) * PSTR + idx * 8);
            acc = __builtin_amdgcn_mfma_f32_16x16x32_f16(af, wf[j], acc, 0, 0, 0);
        }
        int ch = lane & 15;
        if (ch < 8) {
            int pxb = pb + (lane >> 4) * 4;
            #pragma unroll
            for (int r = 0; r < 4; ++r) {
                int px = pxb + r;
                if (px < R1N) s_msg[px * 8 + ch] = (_Float16)acc[r];
            }
        }
    }
    __syncthreads();

    // ---- epilogue 1: Q1 = norm(Q0 * exp(-m1)) in-place in Q plane ----
    for (int i = tid; i < R1N; i += 256) {
        int qy = i / R1W;
        int yy = 1 + qy, xx = i - qy * R1W;
        int gy = gy0 + yy - 2, gx = gx0 + xx - 2;
        if (interior || ((unsigned)gy < (unsigned)H && (unsigned)gx < (unsigned)W)) {
            f16x8 m = *(const f16x8*)(s_msg + i * 8);
            f16x8 q0 = *(const f16x8*)(tb0 + (i + SX) * 8);
            float e[8];
            float s = 0.f;
            #pragma unroll
            for (int o = 0; o < 8; ++o) {
                e[o] = (float)q0[o] * __expf(-(float)m[o]);
                s += e[o];
            }
            float inv = 1.f / s;
            f16x8 q1;
            #pragma unroll
            for (int o = 0; o < 8; ++o) q1[o] = (_Float16)(e[o] * inv);
            *(f16x8*)(tb0 + (i + SX) * 8) = q1;
        }
    }
    // capture m1 for this thread's two output px (s_msg still holds m1)
    f16x8 m1r[2];
    #pragma unroll
    for (int u2 = 0; u2 < 2; ++u2) {
        int i = tid + 256 * u2;
        int oy = i >> 5, ox = i & 31;
        int r1 = (1 + oy) * R1W + (2 + ox);
        m1r[u2] = *(const f16x8*)(s_msg + r1 * 8);
    }
    __syncthreads();

    // ================= iteration 2 MFMA: rows 2..17 x cols 2..33 =================
    for (int t = wv; t < R2T; t += 4) {
        int pb = t * 16;
        int p = pb + (lane & 15);
        int yy = 2 + (p >> 5), xx = 2 + (p & 31);
        int kg = lane >> 4;
        f32x4 acc = {0.f, 0.f, 0.f, 0.f};
        #pragma unroll
        for (int j = 0; j < 5; ++j) {
            int tap = 2 * j + (kg >> 1);
            if (tap > 8) tap = 8;
            int dy = tap / 3 - 1, dx = tap - (tap / 3) * 3 - 1;
            int idx = (yy + dy) * SX + (xx + dx);
            f16x8 af = *(const f16x8*)(tb0 + (kg & 1) * PSTR + idx * 8);
            acc = __builtin_amdgcn_mfma_f32_16x16x32_f16(af, wf[j], acc, 0, 0, 0);
        }
        int ch = lane & 15;
        if (ch < 8) {
            int pxb = pb + (lane >> 4) * 4;
            #pragma unroll
            for (int r = 0; r < 4; ++r) s_msg[(pxb + r) * 8 + ch] = (_Float16)acc[r];
        }
    }
    __syncthreads();

    // ---- epilogue 2: Q2 = norm(Q1 * exp(m1 - m2)); write ----
    #pragma unroll
    for (int u2 = 0; u2 < 2; ++u2) {
        int i = tid + 256 * u2;
        int oy = i >> 5, ox = i & 31;
        int gy = gy0 + oy, gx = gx0 + ox;
        f16x8 m2 = *(const f16x8*)(s_msg + i * 8);
        f16x8 q1 = *(const f16x8*)(tb0 + ((2 + oy) * SX + (2 + ox)) * 8);
        float e[8];
        float s = 0.f;
        #pragma unroll
        for (int o = 0; o < 8; ++o) {
            e[o] = (float)q1[o] * __expf((float)m1r[u2][o] - (float)m2[o]);
            s += e[o];
        }
        float inv = 1.f / s;
        if (UPFOLD) {
            float* qp = (float*)QoutV + (size_t)n * NCLS * HW + (size_t)gy * W + gx;
            int y0, y1, x0, x1;
            float fy, fx;
            ac_prep(gy, 255.f / 511.f, HH, y0, y1, fy);
            ac_prep(gx, 255.f / 511.f, WH, x0, x1, fx);
            const float w00 = (1.f - fy) * (1.f - fx), w01 = (1.f - fy) * fx;
            const float w10 = fy * (1.f - fx), w11 = fy * fx;
            const size_t qb = (size_t)n * (HH * WH);
            f16x8 qa = *(const f16x8*)(Qd + (qb + (size_t)y0 * WH + x0) * 8);
            f16x8 qbv = *(const f16x8*)(Qd + (qb + (size_t)y0 * WH + x1) * 8);
            f16x8 qc = *(const f16x8*)(Qd + (qb + (size_t)y1 * WH + x0) * 8);
            f16x8 qdv = *(const f16x8*)(Qd + (qb + (size_t)y1 * WH + x1) * 8);
            #pragma unroll
            for (int o = 0; o < 8; ++o) {
                float v = w00 * (float)qa[o] + w01 * (float)qbv[o] +
                          w10 * (float)qc[o] + w11 * (float)qdv[o];
                qp[(size_t)o * HW] = fmaf(0.5f, e[o] * inv, 0.5f * v);
            }
        } else {
            _Float16* qo = (_Float16*)QoutV + ((size_t)n * HW + (size_t)gy * W + gx) * 8;
            f16x8 q2;
            #pragma unroll
            for (int o = 0; o < 8; ++o) q2[o] = (_Float16)(e[o] * inv);
            *(f16x8*)qo = q2;
        }
    }
}

static inline int cdiv(int a, int b) { return (a + b - 1) / b; }

extern "C" void kernel_launch(void* const* d_in, const int* in_sizes, int n_in,
                              void* d_out, int out_size, void* d_ws, size_t ws_size,
                              hipStream_t stream) {
    const float* logits = (const float*)d_in[0];
    const float* image = (const float*)d_in[1];
    const float* skip0 = (const float*)d_in[2];
    const float* skip1 = (const float*)d_in[3];
    const float* skip2 = (const float*)d_in[4];
    const float* skip3 = (const float*)d_in[5];
    const float* spatial_w = (const float*)d_in[6];
    const float* bilateral_w = (const float*)d_in[7];
    const float* compat_w = (const float*)d_in[8];
    const float* skip_w0 = (const float*)d_in[9];
    const float* skip_b0 = (const float*)d_in[10];
    const float* skip_w1 = (const float*)d_in[11];
    const float* skip_b1 = (const float*)d_in[12];
    const float* skip_w2 = (const float*)d_in[13];
    const float* skip_b2 = (const float*)d_in[14];
    const float* skip_w3 = (const float*)d_in[15];
    const float* skip_b3 = (const float*)d_in[16];
    float* out = (float*)d_out;
    float* ws = (float*)d_ws;

    // workspace layout (float offsets):
    float* p0 = ws + 0;                    // 1,572,864
    float* p1 = ws + 1572864;              // 393,216
    float* p2 = ws + 1966080;              // 98,304
    float* p3 = ws + 2064384;              // 24,576
    _Float16* wfrag = (_Float16*)(ws + 2110000);   // 2560 halves
    _Float16* Q0h = (_Float16*)(ws + 4194304);     // 8,388,608 floats
    _Float16* Gh = (_Float16*)(ws + 12582912);     // 8,388,608 floats
    _Float16* Qdh = (_Float16*)(ws + 20971520);    // 2,097,152 floats

    const int HWf = HF * WF;

    // --- weight prep (fold compat + MFMA fragments, one kernel) ---
    k_prep_wf<<<1, 1024, 0, stream>>>(spatial_w, bilateral_w, compat_w, wfrag);

    // --- bias fills (one kernel) ---
    k_fill3<<<cdiv(NB * 3 * (16384 + 4096 + 1024), 256), 256, 0, stream>>>(
        p1, p2, p3, skip_b1, skip_b2, skip_b3);

    // --- skip projections (vectorized) ---
    k_skip_proj<4, true><<<cdiv(NB * 16384 * 1, 256), 256, 0, stream>>>(
        skip0, skip_w0, skip_b0, p0, 64, 65536, 1);
    k_skip_proj<4, false><<<cdiv(NB * 4096 * 2, 256), 256, 0, stream>>>(
        skip1, skip_w1, skip_b1, p1, 128, 16384, 2);
    k_skip_proj<2, false><<<cdiv(NB * 2048 * 4, 256), 256, 0, stream>>>(
        skip2, skip_w2, skip_b2, p2, 256, 4096, 4);
    k_skip_proj<1, false><<<cdiv(NB * 1024 * 8, 256), 256, 0, stream>>>(
        skip3, skip_w3, skip_b3, p3, 512, 1024, 8);

    // --- packed guidance + Q0 (fp16 NHWC, 2 px/thread) ---
    k_prep_full<<<cdiv(NB * HWf / 2, 256), 256, 0, stream>>>(
        logits, image, p0, p1, p2, p3, Gh, Q0h);

    // --- half-res mean field: gathers from full-res logits + Gh ---
    {
        dim3 grid(WH / TOX, HH / TOY, NB);
        k_mf_mfma<true, false><<<grid, 256, 0, stream>>>(
            logits, nullptr, Gh, nullptr, (void*)Qdh, wfrag, HH, WH, HF, WF);
    }

    // --- full-res mean field; epilogue folds in 0.5*upsample(Qdh) ---
    {
        dim3 grid(WF / TOX, HF / TOY, NB);
        k_mf_mfma<false, true><<<grid, 256, 0, stream>>>(
            nullptr, Q0h, Gh, Qdh, (void*)out, wfrag, HF, WF, HF, WF);
    }
}

// Round 8
// 195.071 us; speedup vs baseline: 3.7418x; 1.1620x over previous
//
#include <hip/hip_runtime.h>
#include <hip/hip_fp16.h>
#include <math.h>

#define NB 8
#define NCLS 8
#define NGU 6
#define NBI 14
#define HF 512
#define WF 512
#define HH 256
#define WH 256

// MFMA mean-field tile: 32x16 output, 36x20 staged halo
#define TOX 32
#define TOY 16
#define SX 36
#define SY 20
#define SPX (SY * SX)     // 720 staged px
#define R1W 36
#define R1N (18 * 36)     // iter1 region: rows 1..18 x cols 0..35 = 648 px
#define R1T 41            // ceil(648/16)
#define R2T 32
// LDS tile: two planes of [px][8ch] fp16 with zero guards between
#define PLANE (SPX * 8)       // 5760 halves
#define PSTR (PLANE + 32)     // 5792 halves plane stride (guard in between)
#define TILEH (16 + PSTR + PLANE + 16)  // 11584 halves total

typedef _Float16 f16x8 __attribute__((ext_vector_type(8)));
typedef float f32x4 __attribute__((ext_vector_type(4)));

static __device__ __forceinline__ void ac_prep(int o, float scale, int insz,
                                               int& i0, int& i1, float& f) {
    float s = (float)o * scale;
    int ii = (int)floorf(s);
    if (ii > insz - 1) ii = insz - 1;
    if (ii < 0) ii = 0;
    i0 = ii;
    i1 = (ii + 1 < insz) ? (ii + 1) : (insz - 1);
    f = s - (float)ii;
}

// async global->LDS, 16B per lane; LDS base must be wave-uniform
static __device__ __forceinline__ void dma16(const _Float16* g, _Float16* l) {
    __builtin_amdgcn_global_load_lds(
        (const __attribute__((address_space(1))) void*)g,
        (__attribute__((address_space(3))) void*)l, 16, 0, 0);
}

// ---------------- K_init: bias fills for p1..p3 + weight prep (one kernel) ----------------
// blocks 0..2015: fill 516096 floats; block 2016: fold compat + build MFMA fragments.
__global__ __launch_bounds__(256) void k_init(
    float* __restrict__ p1, float* __restrict__ p2, float* __restrict__ p3,
    const float* __restrict__ b1, const float* __restrict__ b2, const float* __restrict__ b3,
    const float* __restrict__ wsp, const float* __restrict__ wbil,
    const float* __restrict__ cw, _Float16* __restrict__ wf) {
    int bid = blockIdx.x;
    int tid = threadIdx.x;
    if (bid < 2016) {
        int i = bid * 256 + tid;
        if (i < NB * 3 * 16384) { p1[i] = b1[(i / 16384) % 3]; return; }
        i -= NB * 3 * 16384;
        if (i < NB * 3 * 4096) { p2[i] = b2[(i / 4096) % 3]; return; }
        i -= NB * 3 * 4096;
        p3[i] = b3[(i / 1024) % 3];
        return;
    }
    // weight block
    __shared__ float sW2[NBI * 72];
    for (int i = tid; i < NBI * 72; i += 256) {
        int o = i & 7;
        int t = (i >> 3) % 9;
        int ci = i / 72;
        float s = 0.f;
        for (int c = 0; c < NCLS; ++c)
            s += cw[o * NCLS + c] * wbil[((size_t)c * NBI + ci) * 9 + t];
        if (ci < NCLS) s += cw[o * NCLS + ci] * wsp[ci * 9 + t];
        sW2[i] = s;
    }
    __syncthreads();
    for (int i = tid; i < 5 * 64; i += 256) {
        int l = i & 63;
        int col = l & 15, kg = l >> 4;
        #pragma unroll
        for (int e = 0; e < 8; ++e) {
            int k = (i >> 6) * 32 + kg * 8 + e;
            int tap = k >> 4, ci = k & 15;
            float v = (tap < 9 && ci < 14 && col < 8) ? sW2[ci * 72 + tap * 8 + col] : 0.f;
            wf[i * 8 + e] = (_Float16)v;
        }
    }
}

// ---------------- skip projection inner (per level) ----------------
template <int VEC, int CH, bool DIRECT>
static __device__ __forceinline__ void skip_level(
    const float* __restrict__ feat, const float* __restrict__ sw,
    const float* __restrict__ bias, float* __restrict__ out,
    int C, int HW, int nch, int idx) {
    const int HWv = HW / VEC;
    int hv = idx % HWv;
    int t = idx / HWv;
    int ch = t % nch;
    int n = t / nch;
    int c0 = ch * CH;
    const float* fp = feat + ((size_t)n * C + c0) * HW + (size_t)hv * VEC;
    float a[3][VEC];
    #pragma unroll
    for (int o = 0; o < 3; ++o)
        #pragma unroll
        for (int k = 0; k < VEC; ++k) a[o][k] = 0.f;
    #pragma unroll 8
    for (int c = 0; c < CH; ++c) {
        float v[VEC];
        if constexpr (VEC == 2) {
            float2 t2 = *reinterpret_cast<const float2*>(fp + (size_t)c * HW);
            v[0] = t2.x; v[1] = t2.y;
        } else {
            v[0] = fp[(size_t)c * HW];
        }
        #pragma unroll
        for (int o = 0; o < 3; ++o) {
            const float wv = sw[o * C + c0 + c];
            #pragma unroll
            for (int k = 0; k < VEC; ++k) a[o][k] = fmaf(wv, v[k], a[o][k]);
        }
    }
    float* op = out + (size_t)n * 3 * HW + (size_t)hv * VEC;
    #pragma unroll
    for (int o = 0; o < 3; ++o) {
        #pragma unroll
        for (int k = 0; k < VEC; ++k) {
            if (DIRECT)
                op[(size_t)o * HW + k] = bias[o] + a[o][k];
            else
                atomicAdd(&op[(size_t)o * HW + k], a[o][k]);
        }
    }
}

// ---------------- K1: ALL skip projections, one kernel, 1024 blocks/level ----------------
__global__ __launch_bounds__(256) void k_skip_all(
    const float* __restrict__ s0, const float* __restrict__ s1,
    const float* __restrict__ s2, const float* __restrict__ s3,
    const float* __restrict__ w0, const float* __restrict__ w1,
    const float* __restrict__ w2, const float* __restrict__ w3,
    const float* __restrict__ b0,
    float* __restrict__ p0, float* __restrict__ p1,
    float* __restrict__ p2, float* __restrict__ p3) {
    __shared__ float sw[3 * 512];
    const int bid = blockIdx.x;
    const int lvl = bid >> 10;
    const int idx = (bid & 1023) * 256 + threadIdx.x;
    const float* w = (lvl == 0) ? w0 : (lvl == 1) ? w1 : (lvl == 2) ? w2 : w3;
    const int C = (lvl == 0) ? 64 : (lvl == 1) ? 128 : (lvl == 2) ? 256 : 512;
    for (int i = threadIdx.x; i < 3 * C; i += 256) sw[i] = w[i];
    __syncthreads();
    if (lvl == 0)      skip_level<2, 64, true >(s0, sw, b0, p0, 64, 65536, 1, idx);
    else if (lvl == 1) skip_level<2, 32, false>(s1, sw, nullptr, p1, 128, 16384, 4, idx);
    else if (lvl == 2) skip_level<1, 32, false>(s2, sw, nullptr, p2, 256, 4096, 8, idx);
    else               skip_level<1, 16, false>(s3, sw, nullptr, p3, 512, 1024, 32, idx);
}

// ---------------- K2: build packed fp16 NHWC guidance + Q0 (2 px/thread) ----------------
__global__ void k_prep_full(const float* __restrict__ logits, const float* __restrict__ image,
                            const float* __restrict__ p0, const float* __restrict__ p1,
                            const float* __restrict__ p2, const float* __restrict__ p3,
                            _Float16* __restrict__ Gh, _Float16* __restrict__ Q0h) {
    const int HW = HF * WF;
    int t = blockIdx.x * blockDim.x + threadIdx.x;
    if (t >= NB * HW / 2) return;
    int idx = t * 2;
    int n = idx / HW, r = idx - n * HW;
    int y = r / WF, x = r - y * WF;

    const float* ps[4] = {p0, p1, p2, p3};
    const int ss[4] = {256, 128, 64, 32};
    float f[2][3] = {{0.f, 0.f, 0.f}, {0.f, 0.f, 0.f}};
    #pragma unroll
    for (int l = 0; l < 4; ++l) {
        int s = ss[l];
        float scale = (float)(s - 1) / 511.0f;
        int y0, y1;
        float fy;
        ac_prep(y, scale, s, y0, y1, fy);
        const float* pb = ps[l] + (size_t)n * 3 * s * s;
        #pragma unroll
        for (int k = 0; k < 2; ++k) {
            int x0, x1;
            float fx;
            ac_prep(x + k, scale, s, x0, x1, fx);
            #pragma unroll
            for (int o = 0; o < 3; ++o) {
                const float* pp = pb + (size_t)o * s * s;
                float v00 = pp[y0 * s + x0], v01 = pp[y0 * s + x1];
                float v10 = pp[y1 * s + x0], v11 = pp[y1 * s + x1];
                float r0 = v00 * (1.f - fy) + v10 * fy;
                float r1 = v01 * (1.f - fy) + v11 * fy;
                f[k][o] += r0 * (1.f - fx) + r1 * fx;
            }
        }
    }
    const float* ip = image + (size_t)n * 3 * HW + r;
    float2 img[3];
    #pragma unroll
    for (int o = 0; o < 3; ++o) img[o] = *reinterpret_cast<const float2*>(&ip[(size_t)o * HW]);
    const float* up = logits + (size_t)n * NCLS * HW + r;
    float2 u[8];
    #pragma unroll
    for (int o = 0; o < 8; ++o) u[o] = *reinterpret_cast<const float2*>(&up[(size_t)o * HW]);

    f16x8 gv[2], qv[2];
    #pragma unroll
    for (int k = 0; k < 2; ++k) {
        gv[k][0] = (_Float16)(k ? img[0].y : img[0].x);
        gv[k][1] = (_Float16)(k ? img[1].y : img[1].x);
        gv[k][2] = (_Float16)(k ? img[2].y : img[2].x);
        gv[k][3] = (_Float16)(f[k][0] * 0.25f);
        gv[k][4] = (_Float16)(f[k][1] * 0.25f);
        gv[k][5] = (_Float16)(f[k][2] * 0.25f);
        gv[k][6] = (_Float16)0.f;
        gv[k][7] = (_Float16)0.f;
        float e[8];
        float s = 0.f;
        #pragma unroll
        for (int o = 0; o < 8; ++o) { e[o] = __expf(k ? u[o].y : u[o].x); s += e[o]; }
        float inv = 1.f / s;
        #pragma unroll
        for (int o = 0; o < 8; ++o) qv[k][o] = (_Float16)(e[o] * inv);
    }
    *(f16x8*)(Gh + (size_t)idx * 8) = gv[0];
    *(f16x8*)(Gh + (size_t)idx * 8 + 8) = gv[1];
    *(f16x8*)(Q0h + (size_t)idx * 8) = qv[0];
    *(f16x8*)(Q0h + (size_t)idx * 8 + 8) = qv[1];
}

// ---------------- K5: both mean-field iterations, conv on MFMA ----------------
// DOWN:   staging bilinear-gathers logits (fp32) + Gh (fp16) from full-res.
// !DOWN:  interior blocks DMA-stage via global_load_lds; boundary blocks masked path.
// UPFOLD: out(fp32 planar) = 0.5*Q2 + 0.5*bilerp(Qd fp16 NHWC); else write fp16 NHWC.
template <bool DOWN, bool UPFOLD>
__global__ __launch_bounds__(256, 4) void k_mf_mfma(
    const float* __restrict__ unary, const _Float16* __restrict__ Q0h,
    const _Float16* __restrict__ Gh, const _Float16* __restrict__ Qd,
    void* __restrict__ QoutV, const _Float16* __restrict__ wfragG,
    int H, int W, int Hs, int Ws) {
    __shared__ __align__(16) _Float16 s_t[TILEH];
    __shared__ __align__(16) _Float16 s_msg[R1N * 8];
    _Float16* tb0 = s_t + 16;            // Q plane (ci 0..7)
    _Float16* tb1 = s_t + 16 + PSTR;     // guid plane (ci 8..15)

    const int tid = threadIdx.x;
    const int lane = tid & 63;
    const int wv = tid >> 6;
    const int n = blockIdx.z;
    const int gx0 = blockIdx.x * TOX;
    const int gy0 = blockIdx.y * TOY;
    const int HW = H * W;
    const int HWs = Hs * Ws;

    // weight fragments (wave-uniform, L2-broadcast)
    f16x8 wf[5];
    #pragma unroll
    for (int j = 0; j < 5; ++j)
        wf[j] = *(const f16x8*)(wfragG + (j * 64 + lane) * 8);

    // zero guard pads: [0,16), [5776,5808), [11568,11584)
    if (tid < 16) s_t[tid] = (_Float16)0.f;
    else if (tid < 48) s_t[5760 + tid] = (_Float16)0.f;
    else if (tid < 64) s_t[11520 + tid] = (_Float16)0.f;

    const bool interior = !DOWN && gx0 >= 2 && (gx0 + TOX + 2) <= W &&
                          gy0 >= 2 && (gy0 + TOY + 2) <= H;

    if (!DOWN && interior) {
        // ---- fast staging: async DMA, 64 px per chunk, 12 chunks per plane ----
        const size_t nb = (size_t)n * HW;
        for (int c = wv; c < 12; c += 4) {
            int px = c * 64 + lane;
            int yy = px / SX, xx = px - yy * SX;
            size_t goff = (nb + (size_t)(gy0 + yy - 2) * W + (gx0 + xx - 2)) * 8;
            if (px < SPX) {
                dma16(Q0h + goff, tb0 + (size_t)c * 64 * 8);
                dma16(Gh + goff, tb1 + (size_t)c * 64 * 8);
            }
        }
    } else {
        const float syc = DOWN ? (float)(Hs - 1) / (float)(H - 1) : 1.f;
        const float sxc = DOWN ? (float)(Ws - 1) / (float)(W - 1) : 1.f;
        for (int i = tid; i < SPX; i += 256) {
            int yy = i / SX, xx = i - yy * SX;
            int gy = gy0 + yy - 2, gx = gx0 + xx - 2;
            f16x8 qv, gv;
            #pragma unroll
            for (int o = 0; o < 8; ++o) { qv[o] = (_Float16)0.f; gv[o] = (_Float16)0.f; }
            if ((unsigned)gy < (unsigned)H && (unsigned)gx < (unsigned)W) {
                if (DOWN) {
                    int y0, y1, x0, x1;
                    float fy, fx;
                    ac_prep(gy, syc, Hs, y0, y1, fy);
                    ac_prep(gx, sxc, Ws, x0, x1, fx);
                    const float w00 = (1.f - fy) * (1.f - fx), w01 = (1.f - fy) * fx;
                    const float w10 = fy * (1.f - fx), w11 = fy * fx;
                    const size_t o00 = (size_t)y0 * Ws + x0, o01 = (size_t)y0 * Ws + x1;
                    const size_t o10 = (size_t)y1 * Ws + x0, o11 = (size_t)y1 * Ws + x1;
                    const float* ubase = unary + (size_t)n * NCLS * HWs;
                    float e[8];
                    float s = 0.f;
                    #pragma unroll
                    for (int o = 0; o < 8; ++o) {
                        const float* up = ubase + (size_t)o * HWs;
                        float u = w00 * up[o00] + w01 * up[o01] + w10 * up[o10] + w11 * up[o11];
                        e[o] = __expf(u);
                        s += e[o];
                    }
                    float inv = 1.f / s;
                    #pragma unroll
                    for (int o = 0; o < 8; ++o) qv[o] = (_Float16)(e[o] * inv);
                    const size_t gb = (size_t)n * HWs;
                    f16x8 ga = *(const f16x8*)(Gh + (gb + o00) * 8);
                    f16x8 gb2 = *(const f16x8*)(Gh + (gb + o01) * 8);
                    f16x8 gc = *(const f16x8*)(Gh + (gb + o10) * 8);
                    f16x8 gd = *(const f16x8*)(Gh + (gb + o11) * 8);
                    #pragma unroll
                    for (int c = 0; c < 8; ++c) {
                        float g = w00 * (float)ga[c] + w01 * (float)gb2[c] +
                                  w10 * (float)gc[c] + w11 * (float)gd[c];
                        gv[c] = (_Float16)g;
                    }
                } else {
                    const size_t off = ((size_t)n * HW + (size_t)gy * W + gx) * 8;
                    qv = *(const f16x8*)(Q0h + off);
                    gv = *(const f16x8*)(Gh + off);
                }
            }
            *(f16x8*)(tb0 + i * 8) = qv;
            *(f16x8*)(tb1 + i * 8) = gv;
        }
    }
    __syncthreads();

    // ================= iteration 1 MFMA: rows 1..18 x cols 0..35 =================
    for (int t = wv; t < R1T; t += 4) {
        int pb = t * 16;
        int p = pb + (lane & 15);
        if (p > R1N - 1) p = R1N - 1;
        int qy = p / R1W;
        int yy = 1 + qy, xx = p - qy * R1W;
        int kg = lane >> 4;
        f32x4 acc = {0.f, 0.f, 0.f, 0.f};
        #pragma unroll
        for (int j = 0; j < 5; ++j) {
            int tap = 2 * j + (kg >> 1);
            if (tap > 8) tap = 8;
            int dy = tap / 3 - 1, dx = tap - (tap / 3) * 3 - 1;
            int idx = (yy + dy) * SX + (xx + dx);
            f16x8 af = *(const f16x8*)(tb0 + (kg & 1) * PSTR + idx * 8);
            acc = __builtin_amdgcn_mfma_f32_16x16x32_f16(af, wf[j], acc, 0, 0, 0);
        }
        int ch = lane & 15;
        if (ch < 8) {
            int pxb = pb + (lane >> 4) * 4;
            #pragma unroll
            for (int r = 0; r < 4; ++r) {
                int px = pxb + r;
                if (px < R1N) s_msg[px * 8 + ch] = (_Float16)acc[r];
            }
        }
    }
    __syncthreads();

    // ---- epilogue 1: Q1 = norm(Q0 * exp(-m1)) in-place in Q plane ----
    for (int i = tid; i < R1N; i += 256) {
        int qy = i / R1W;
        int yy = 1 + qy, xx = i - qy * R1W;
        int gy = gy0 + yy - 2, gx = gx0 + xx - 2;
        if (interior || ((unsigned)gy < (unsigned)H && (unsigned)gx < (unsigned)W)) {
            f16x8 m = *(const f16x8*)(s_msg + i * 8);
            f16x8 q0 = *(const f16x8*)(tb0 + (i + SX) * 8);
            float e[8];
            float s = 0.f;
            #pragma unroll
            for (int o = 0; o < 8; ++o) {
                e[o] = (float)q0[o] * __expf(-(float)m[o]);
                s += e[o];
            }
            float inv = 1.f / s;
            f16x8 q1;
            #pragma unroll
            for (int o = 0; o < 8; ++o) q1[o] = (_Float16)(e[o] * inv);
            *(f16x8*)(tb0 + (i + SX) * 8) = q1;
        }
    }
    // capture m1 for this thread's two output px (s_msg still holds m1)
    f16x8 m1r[2];
    #pragma unroll
    for (int u2 = 0; u2 < 2; ++u2) {
        int i = tid + 256 * u2;
        int oy = i >> 5, ox = i & 31;
        int r1 = (1 + oy) * R1W + (2 + ox);
        m1r[u2] = *(const f16x8*)(s_msg + r1 * 8);
    }
    __syncthreads();

    // ================= iteration 2 MFMA: rows 2..17 x cols 2..33 =================
    for (int t = wv; t < R2T; t += 4) {
        int pb = t * 16;
        int p = pb + (lane & 15);
        int yy = 2 + (p >> 5), xx = 2 + (p & 31);
        int kg = lane >> 4;
        f32x4 acc = {0.f, 0.f, 0.f, 0.f};
        #pragma unroll
        for (int j = 0; j < 5; ++j) {
            int tap = 2 * j + (kg >> 1);
            if (tap > 8) tap = 8;
            int dy = tap / 3 - 1, dx = tap - (tap / 3) * 3 - 1;
            int idx = (yy + dy) * SX + (xx + dx);
            f16x8 af = *(const f16x8*)(tb0 + (kg & 1) * PSTR + idx * 8);
            acc = __builtin_amdgcn_mfma_f32_16x16x32_f16(af, wf[j], acc, 0, 0, 0);
        }
        int ch = lane & 15;
        if (ch < 8) {
            int pxb = pb + (lane >> 4) * 4;
            #pragma unroll
            for (int r = 0; r < 4; ++r) s_msg[(pxb + r) * 8 + ch] = (_Float16)acc[r];
        }
    }
    __syncthreads();

    // ---- epilogue 2: Q2 = norm(Q1 * exp(m1 - m2)); write ----
    #pragma unroll
    for (int u2 = 0; u2 < 2; ++u2) {
        int i = tid + 256 * u2;
        int oy = i >> 5, ox = i & 31;
        int gy = gy0 + oy, gx = gx0 + ox;
        f16x8 m2 = *(const f16x8*)(s_msg + i * 8);
        f16x8 q1 = *(const f16x8*)(tb0 + ((2 + oy) * SX + (2 + ox)) * 8);
        float e[8];
        float s = 0.f;
        #pragma unroll
        for (int o = 0; o < 8; ++o) {
            e[o] = (float)q1[o] * __expf((float)m1r[u2][o] - (float)m2[o]);
            s += e[o];
        }
        float inv = 1.f / s;
        if (UPFOLD) {
            float* qp = (float*)QoutV + (size_t)n * NCLS * HW + (size_t)gy * W + gx;
            int y0, y1, x0, x1;
            float fy, fx;
            ac_prep(gy, 255.f / 511.f, HH, y0, y1, fy);
            ac_prep(gx, 255.f / 511.f, WH, x0, x1, fx);
            const float w00 = (1.f - fy) * (1.f - fx), w01 = (1.f - fy) * fx;
            const float w10 = fy * (1.f - fx), w11 = fy * fx;
            const size_t qb = (size_t)n * (HH * WH);
            f16x8 qa = *(const f16x8*)(Qd + (qb + (size_t)y0 * WH + x0) * 8);
            f16x8 qbv = *(const f16x8*)(Qd + (qb + (size_t)y0 * WH + x1) * 8);
            f16x8 qc = *(const f16x8*)(Qd + (qb + (size_t)y1 * WH + x0) * 8);
            f16x8 qdv = *(const f16x8*)(Qd + (qb + (size_t)y1 * WH + x1) * 8);
            #pragma unroll
            for (int o = 0; o < 8; ++o) {
                float v = w00 * (float)qa[o] + w01 * (float)qbv[o] +
                          w10 * (float)qc[o] + w11 * (float)qdv[o];
                qp[(size_t)o * HW] = fmaf(0.5f, e[o] * inv, 0.5f * v);
            }
        } else {
            _Float16* qo = (_Float16*)QoutV + ((size_t)n * HW + (size_t)gy * W + gx) * 8;
            f16x8 q2;
            #pragma unroll
            for (int o = 0; o < 8; ++o) q2[o] = (_Float16)(e[o] * inv);
            *(f16x8*)qo = q2;
        }
    }
}

static inline int cdiv(int a, int b) { return (a + b - 1) / b; }

extern "C" void kernel_launch(void* const* d_in, const int* in_sizes, int n_in,
                              void* d_out, int out_size, void* d_ws, size_t ws_size,
                              hipStream_t stream) {
    const float* logits = (const float*)d_in[0];
    const float* image = (const float*)d_in[1];
    const float* skip0 = (const float*)d_in[2];
    const float* skip1 = (const float*)d_in[3];
    const float* skip2 = (const float*)d_in[4];
    const float* skip3 = (const float*)d_in[5];
    const float* spatial_w = (const float*)d_in[6];
    const float* bilateral_w = (const float*)d_in[7];
    const float* compat_w = (const float*)d_in[8];
    const float* skip_w0 = (const float*)d_in[9];
    const float* skip_b0 = (const float*)d_in[10];
    const float* skip_w1 = (const float*)d_in[11];
    const float* skip_b1 = (const float*)d_in[12];
    const float* skip_w2 = (const float*)d_in[13];
    const float* skip_b2 = (const float*)d_in[14];
    const float* skip_w3 = (const float*)d_in[15];
    const float* skip_b3 = (const float*)d_in[16];
    float* out = (float*)d_out;
    float* ws = (float*)d_ws;

    // workspace layout (float offsets):
    float* p0 = ws + 0;                    // 1,572,864
    float* p1 = ws + 1572864;              // 393,216
    float* p2 = ws + 1966080;              // 98,304
    float* p3 = ws + 2064384;              // 24,576
    _Float16* wfrag = (_Float16*)(ws + 2110000);   // 2560 halves
    _Float16* Q0h = (_Float16*)(ws + 4194304);     // 8,388,608 floats
    _Float16* Gh = (_Float16*)(ws + 12582912);     // 8,388,608 floats
    _Float16* Qdh = (_Float16*)(ws + 20971520);    // 2,097,152 floats

    const int HWf = HF * WF;

    // --- init: bias fills + weight prep (one kernel) ---
    k_init<<<2017, 256, 0, stream>>>(p1, p2, p3, skip_b1, skip_b2, skip_b3,
                                     spatial_w, bilateral_w, compat_w, wfrag);

    // --- all skip projections (one kernel, 4096 blocks) ---
    k_skip_all<<<4096, 256, 0, stream>>>(skip0, skip1, skip2, skip3,
                                         skip_w0, skip_w1, skip_w2, skip_w3,
                                         skip_b0, p0, p1, p2, p3);

    // --- packed guidance + Q0 (fp16 NHWC, 2 px/thread) ---
    k_prep_full<<<cdiv(NB * HWf / 2, 256), 256, 0, stream>>>(
        logits, image, p0, p1, p2, p3, Gh, Q0h);

    // --- half-res mean field: gathers from full-res logits + Gh ---
    {
        dim3 grid(WH / TOX, HH / TOY, NB);
        k_mf_mfma<true, false><<<grid, 256, 0, stream>>>(
            logits, nullptr, Gh, nullptr, (void*)Qdh, wfrag, HH, WH, HF, WF);
    }

    // --- full-res mean field; epilogue folds in 0.5*upsample(Qdh) ---
    {
        dim3 grid(WF / TOX, HF / TOY, NB);
        k_mf_mfma<false, true><<<grid, 256, 0, stream>>>(
            nullptr, Q0h, Gh, Qdh, (void*)out, wfrag, HF, WF, HF, WF);
    }
}